// Round 9
// baseline (443.619 us; speedup 1.0000x reference)
//
#include <hip/hip_runtime.h>

#define BNn 65536L   // B*N

typedef unsigned short u16;
typedef unsigned int u32;
typedef __attribute__((ext_vector_type(8))) short short8;
typedef __attribute__((ext_vector_type(4))) float f32x4;

__device__ inline u16 f2b(float f){ u32 u = __float_as_uint(f); u32 r = (u + 0x7fffu + ((u>>16)&1u))>>16; return (u16)r; }
__device__ inline float b2f(u16 b){ return __uint_as_float(((u32)b)<<16); }

// ---------------------------------------------------------------- init: blocks 0..40 weight prep (+zero), 41.. embed (+deg)
__global__ __launch_bounds__(256) void k_init(const float* __restrict__ gcnW, const float* __restrict__ tcW,
                       const float* __restrict__ sgW, const float* __restrict__ dKW,
                       const float* __restrict__ dVW,
                       const float* __restrict__ Wq, const float* __restrict__ Wk, const float* __restrict__ Wv,
                       const float* __restrict__ in, const float* __restrict__ Wi, const float* __restrict__ bi,
                       const int* __restrict__ adj, float* __restrict__ dinv,
                       u16* __restrict__ wts, float* __restrict__ SqSkz, u16* __restrict__ x0) {
  __shared__ u16 sT[64 * 136];
  __shared__ float Ws[1024];
  __shared__ float bs[128];
  __shared__ float ins[256];
  int bid = blockIdx.x, t = threadIdx.x;
  if (bid < 41) {
    if (bid == 40) {
      if (t < 130) SqSkz[t] = 0.0f;   // Sq, Sk, zsum
      return;
    }
    const float* src; long dst; int lds_src;
    if (bid < 16) {
      int mtx = bid >> 1, kh = bid & 1;
      src = (mtx < 4 ? gcnW + mtx * 16384 : mtx == 4 ? tcW : mtx == 5 ? sgW : mtx == 6 ? dKW : dVW) + kh * 64 * 128;
      dst = (long)mtx * 16384 + kh * 64;
      lds_src = 128;
    } else {
      int q = bid - 16; int mat = q >> 3, rem = q & 7, kh = rem >> 2, cb = rem & 3;
      src = (mat == 0 ? Wq : mat == 1 ? Wk : Wv) + kh * 64 * 512 + cb * 128;
      dst = 131072L + (long)(mat * 512 + cb * 128) * 128 + kh * 64;
      lds_src = 512;
    }
#pragma unroll
    for (int i = 0; i < 32; i++) {
      int idx = t + i * 256; int row = idx >> 7, col = idx & 127;
      sT[row * 136 + col] = f2b(src[(long)row * lds_src + col]);
    }
    __syncthreads();
    {
      int n = t >> 1, kb = t & 1;
      u16 ob[32];
#pragma unroll
      for (int k = 0; k < 32; k++) ob[k] = sT[(kb * 32 + k) * 136 + n];
      uint4* o4 = (uint4*)(wts + dst + (long)n * 128 + kb * 32);
      uint4* s4 = (uint4*)ob;
#pragma unroll
      for (int k = 0; k < 4; k++) o4[k] = s4[k];
    }
    return;
  }
  int b = bid - 41;   // 0..2047
  long row0 = (long)b * 32;
  if (b < 256) {
    int n = b * 256 + t;
    int cnt = 0;
#pragma unroll
    for (int j = 0; j < 16; j++) cnt += (adj[(long)n * 16 + j] >= 0) ? 1 : 0;
    dinv[n] = rsqrtf((float)cnt + 1.0f);
  }
#pragma unroll
  for (int i = 0; i < 4; i++) Ws[t + i * 256] = Wi[t + i * 256];
  if (t < 128) bs[t] = bi[t];
  ins[t] = in[row0 * 8 + t];
  __syncthreads();
  int row = t >> 3, seg = t & 7;
  float acc[16];
#pragma unroll
  for (int i = 0; i < 16; i++) acc[i] = bs[seg * 16 + i];
#pragma unroll
  for (int k = 0; k < 8; k++) {
    float f = ins[row * 8 + k];
#pragma unroll
    for (int i = 0; i < 16; i++) acc[i] += f * Ws[k * 128 + seg * 16 + i];
  }
  u16 ob[16];
#pragma unroll
  for (int i = 0; i < 16; i++) ob[i] = f2b(acc[i]);
  uint4* o4 = (uint4*)(x0 + (row0 + row) * 128 + seg * 16);
  uint4* s4 = (uint4*)ob;
  o4[0] = s4[0]; o4[1] = s4[1];
}

// ---------------------------------------------------------------- MFMA GEMM: 128 rows/block, W in LDS, A in regs
template<int EPI>
__global__ __launch_bounds__(256) void k_gemm(const u16* __restrict__ A,
                                              const u16* __restrict__ WT,
                                              const float* __restrict__ bias,
                                              const float* __restrict__ lng,
                                              const float* __restrict__ lnb,
                                              u16* __restrict__ C,
                                              u16* __restrict__ CT) {
  __shared__ u16 sW[128 * 136];
  int t = threadIdx.x;
  long row0 = (long)blockIdx.x * 128;
  int wave = t >> 6, lane = t & 63, m = lane & 15, g = lane >> 4;
#pragma unroll
  for (int i = 0; i < 8; i++) {
    int idx = t + i * 256; int row = idx >> 4, ch = idx & 15;
    *(float4*)(sW + row * 136 + ch * 8) = *(const float4*)(WT + row * 128 + ch * 8);
  }
  short8 a[2][4];
#pragma unroll
  for (int i = 0; i < 2; i++) {
    const u16* aG = A + (row0 + wave * 32 + i * 16 + m) * 128 + g * 8;
#pragma unroll
    for (int s = 0; s < 4; s++) a[i][s] = *(const short8*)(aG + s * 32);
  }
  __syncthreads();
  f32x4 acc[2][8];
#pragma unroll
  for (int i = 0; i < 2; i++)
#pragma unroll
    for (int c = 0; c < 8; c++) acc[i][c] = (f32x4){0.f, 0.f, 0.f, 0.f};
#pragma unroll
  for (int s = 0; s < 4; s++) {
#pragma unroll
    for (int c = 0; c < 8; c++) {
      short8 bb = *(const short8*)(sW + (c * 16 + m) * 136 + g * 8 + s * 32);
      acc[0][c] = __builtin_amdgcn_mfma_f32_16x16x32_bf16(a[0][s], bb, acc[0][c], 0, 0, 0);
      acc[1][c] = __builtin_amdgcn_mfma_f32_16x16x32_bf16(a[1][s], bb, acc[1][c], 0, 0, 0);
    }
  }
#pragma unroll
  for (int c = 0; c < 8; c++) {
    float bc = bias ? bias[c * 16 + m] : 0.0f;
#pragma unroll
    for (int i = 0; i < 2; i++)
#pragma unroll
      for (int r = 0; r < 4; r++) acc[i][c][r] += bc;
  }
  if (EPI == 2) {
    float gg[8], bb2[8];
#pragma unroll
    for (int c = 0; c < 8; c++) { gg[c] = lng[c * 16 + m]; bb2[c] = lnb[c * 16 + m]; }
#pragma unroll
    for (int i = 0; i < 2; i++)
#pragma unroll
      for (int r = 0; r < 4; r++) {
        float s1 = 0.f, s2 = 0.f;
#pragma unroll
        for (int c = 0; c < 8; c++) { float y = acc[i][c][r]; s1 += y; s2 += y * y; }
#pragma unroll
        for (int mask = 1; mask < 16; mask <<= 1) { s1 += __shfl_xor(s1, mask); s2 += __shfl_xor(s2, mask); }
        float mu = s1 * (1.f / 128.f);
        float rstd = rsqrtf(s2 * (1.f / 128.f) - mu * mu + 1e-5f);
#pragma unroll
        for (int c = 0; c < 8; c++)
          acc[i][c][r] = fmaxf((acc[i][c][r] - mu) * rstd * gg[c] + bb2[c], 0.f);
      }
  }
#pragma unroll
  for (int i = 0; i < 2; i++) {
    long rb = row0 + wave * 32 + i * 16 + g * 4;
#pragma unroll
    for (int c = 0; c < 8; c++) {
      int col = c * 16 + m;
      u16 ob[4];
#pragma unroll
      for (int r = 0; r < 4; r++) {
        float y = acc[i][c][r];
        if (EPI == 1) y = fmaxf(y, 0.f);
        ob[r] = f2b(y);
        C[(rb + r) * 128 + col] = ob[r];
      }
      if (CT) {
        uint2 p;
        p.x = ((u32)ob[1] << 16) | ob[0]; p.y = ((u32)ob[3] << 16) | ob[2];
        *(uint2*)(CT + (long)col * BNn + rb) = p;
      }
    }
  }
}

// ---------------------------------------------------------------- fused GCN layer: 256 threads, 64 rows/block, XCD swizzle
// v2: neighbor gather batched 4-at-a-time (16 uint4 in flight) for MLP depth.
__global__ __launch_bounds__(256) void k_gcn(const u16* __restrict__ h,
                                             const u16* __restrict__ WT,
                                             const int* __restrict__ adj,
                                             const float* __restrict__ dinv,
                                             const float* __restrict__ gb,
                                             u16* __restrict__ out, int relu) {
  __shared__ u16 sA[64 * 132];
  __shared__ u16 sW[128 * 132];
  int t = threadIdx.x;
  int lane = t & 63;
  int p = blockIdx.x;
  long n0 = ((long)(p & 63) << 10) + ((long)(p >> 6) << 6);   // graph*1024 + tile*64
#pragma unroll
  for (int i = 0; i < 8; i++) {
    int idx = t + i * 256; int row = idx >> 4, ch = idx & 15;
    *(float4*)(sW + row * 132 + ch * 8) = *(const float4*)(WT + row * 128 + ch * 8);
  }
  {
    int row = t >> 2, seg = t & 3;
    long n = n0 + row;
    float din = dinv[n];
    float d2v = din * din;
    int4 a4 = *(const int4*)(adj + n * 16 + seg * 4);
    int cols[4]; float enq[4];
    int bb = ((int)(n >> 10)) << 10;
    const int* ap = &a4.x;
#pragma unroll
    for (int q = 0; q < 4; q++) {
      int a = ap[q];
      int valid = a >= 0;
      int cc = (valid ? a : 0) + bb;
      cols[q] = cc;
      enq[q] = valid ? din * dinv[cc] : 0.0f;
    }
    float acc[32];
    {
      const u16* hr = h + n * 128 + seg * 32;
      uint4 v0 = *(const uint4*)(hr), v1 = *(const uint4*)(hr + 8), v2 = *(const uint4*)(hr + 16), v3 = *(const uint4*)(hr + 24);
      const u16* pv = (const u16*)&v0;
#pragma unroll
      for (int i = 0; i < 8; i++) acc[i] = b2f(pv[i]) * d2v;
      pv = (const u16*)&v1;
#pragma unroll
      for (int i = 0; i < 8; i++) acc[8 + i] = b2f(pv[i]) * d2v;
      pv = (const u16*)&v2;
#pragma unroll
      for (int i = 0; i < 8; i++) acc[16 + i] = b2f(pv[i]) * d2v;
      pv = (const u16*)&v3;
#pragma unroll
      for (int i = 0; i < 8; i++) acc[24 + i] = b2f(pv[i]) * d2v;
    }
#pragma unroll
    for (int jb = 0; jb < 4; jb++) {
      int cc4[4]; float e4[4];
      uint4 nv[16];
#pragma unroll
      for (int q = 0; q < 4; q++) {
        int j = jb * 4 + q;
        int src = (lane & 60) | (j >> 2);
        cc4[q] = __shfl(cols[j & 3], src);
        e4[q] = __shfl(enq[j & 3], src);
        const u16* nb = h + (long)cc4[q] * 128 + seg * 32;
        nv[q * 4 + 0] = *(const uint4*)(nb);
        nv[q * 4 + 1] = *(const uint4*)(nb + 8);
        nv[q * 4 + 2] = *(const uint4*)(nb + 16);
        nv[q * 4 + 3] = *(const uint4*)(nb + 24);
      }
#pragma unroll
      for (int q = 0; q < 4; q++) {
        float e = e4[q];
#pragma unroll
        for (int v = 0; v < 4; v++) {
          const u16* pv = (const u16*)&nv[q * 4 + v];
#pragma unroll
          for (int i = 0; i < 8; i++) acc[v * 8 + i] += e * b2f(pv[i]);
        }
      }
    }
    u16 ob[32];
#pragma unroll
    for (int i = 0; i < 32; i++) ob[i] = f2b(acc[i]);
    uint4* o4 = (uint4*)(sA + row * 132 + seg * 32);
    uint4* s4 = (uint4*)ob;
#pragma unroll
    for (int i = 0; i < 4; i++) o4[i] = s4[i];
  }
  __syncthreads();
  int wave = t >> 6, m = lane & 15, g = lane >> 4;
  const u16* aB = sA + (wave * 16 + m) * 132 + g * 8;
  short8 a[4];
#pragma unroll
  for (int s = 0; s < 4; s++) a[s] = *(const short8*)(aB + s * 32);
  f32x4 acc[8];
#pragma unroll
  for (int c = 0; c < 8; c++) {
    float bc = gb[c * 16 + m];
    acc[c] = (f32x4){bc, bc, bc, bc};
  }
#pragma unroll
  for (int s = 0; s < 4; s++) {
#pragma unroll
    for (int c = 0; c < 8; c++) {
      short8 bb = *(const short8*)(sW + (c * 16 + m) * 132 + g * 8 + s * 32);
      acc[c] = __builtin_amdgcn_mfma_f32_16x16x32_bf16(a[s], bb, acc[c], 0, 0, 0);
    }
  }
#pragma unroll
  for (int c = 0; c < 8; c++) {
    int col = c * 16 + m;
#pragma unroll
    for (int r = 0; r < 4; r++) {
      float y = acc[c][r];
      if (relu) y = fmaxf(y, 0.f);
      out[(n0 + wave * 16 + g * 4 + r) * 128 + col] = f2b(y);
    }
  }
}

// ---------------------------------------------------------------- Gram: 2 slices/block, Gpart[128], + zsum
__global__ __launch_bounds__(256) void k_gram(const u16* __restrict__ z0T,
                                              float* __restrict__ Gpart, float* __restrict__ zsum) {
  __shared__ u16 sZT[128 * 264];
  int t = threadIdx.x;
  int wave = t >> 6, lane = t & 63, m = lane & 15, g = lane >> 4;
  f32x4 acc[2][8];
#pragma unroll
  for (int i = 0; i < 2; i++)
#pragma unroll
    for (int c = 0; c < 8; c++) acc[i][c] = (f32x4){0.f, 0.f, 0.f, 0.f};
  float zs = 0.f;
  for (int sl = 0; sl < 2; sl++) {
    long k0 = (long)(blockIdx.x * 2 + sl) * 256;
    __syncthreads();
#pragma unroll
    for (int i = 0; i < 16; i++) {
      int idx = t + i * 256; int mm = idx >> 5, ch = idx & 31;
      *(float4*)(sZT + mm * 264 + ch * 8) = *(const float4*)(z0T + (long)mm * BNn + k0 + ch * 8);
    }
    __syncthreads();
#pragma unroll
    for (int kk = 0; kk < 8; kk++) {
      short8 a0 = *(const short8*)(sZT + (wave * 32 + m) * 264 + kk * 32 + g * 8);
      short8 a1 = *(const short8*)(sZT + (wave * 32 + 16 + m) * 264 + kk * 32 + g * 8);
#pragma unroll
      for (int c = 0; c < 8; c++) {
        short8 bb = *(const short8*)(sZT + (c * 16 + m) * 264 + kk * 32 + g * 8);
        acc[0][c] = __builtin_amdgcn_mfma_f32_16x16x32_bf16(a0, bb, acc[0][c], 0, 0, 0);
        acc[1][c] = __builtin_amdgcn_mfma_f32_16x16x32_bf16(a1, bb, acc[1][c], 0, 0, 0);
      }
    }
    if (t < 128) {
      float s = 0.f;
      for (int j = 0; j < 256; j++) s += b2f(sZT[t * 264 + j]);
      zs += s;
    }
  }
  if (t < 128) atomicAdd(&zsum[t], zs);
  float* P = Gpart + (long)blockIdx.x * 16384 + wave * 4096;
#pragma unroll
  for (int i = 0; i < 2; i++)
#pragma unroll
    for (int c = 0; c < 8; c++)
      *(f32x4*)(P + (i * 8 + c) * 256 + lane * 4) = acc[i][c];
}

// ---------------------------------------------------------------- reduce Gram partials -> G fp32 [128][128]
__global__ void k_gram_red(const float* __restrict__ Gpart, float* __restrict__ G) {
  int o = blockIdx.x * 256 + threadIdx.x;   // 0..16383
  float s = 0.f;
  for (int b = 0; b < 128; b++) s += Gpart[(long)b * 16384 + o];
  int wave = o >> 12, rem = o & 4095;
  int ic = rem >> 8, i = ic >> 3, c = ic & 7;
  int rem2 = rem & 255, lane = rem2 >> 2, q = rem2 & 3;
  int m = lane & 15, g = lane >> 4;
  int mi = wave * 32 + i * 16 + g * 4 + q;
  int mj = c * 16 + m;
  G[mi * 128 + mj] = s;
}

// ---------------------------------------------------------------- merged stats + kvsT
__global__ __launch_bounds__(256) void k_statskvs(const float* __restrict__ Wq, const float* __restrict__ bq,
                                                  const float* __restrict__ Wk, const float* __restrict__ bk,
                                                  const float* __restrict__ Wv, const float* __restrict__ bv,
                                                  const float* __restrict__ G, const float* __restrict__ zsum,
                                                  float* __restrict__ ksum,
                                                  float* __restrict__ Sq, float* __restrict__ Sk,
                                                  u16* __restrict__ kvsT) {
  int t = threadIdx.x;
  int blk = blockIdx.x;
  if (blk < 2) {
    int c = blk * 256 + t;
    float s = 0.f;
    for (int i = 0; i < 128; i++) s += Wk[i * 512 + c] * zsum[i];
    ksum[c] = s + 65536.0f * bk[c];
    return;
  }
  if (blk < 130) {
    __shared__ float wcol[128];
    __shared__ float red[256];
    int bi = blk - 2;
    int isK = bi >> 6;
    const float* W = isK ? Wk : Wq;
    const float* bb = isK ? bk : bq;
    float* S = isK ? Sk : Sq;
    int c0 = (bi & 63) * 8;
    float tot = 0.f;
    for (int cc = 0; cc < 8; cc++) {
      int c = c0 + cc;
      __syncthreads();
      if (t < 128) wcol[t] = W[t * 512 + c];
      __syncthreads();
      float v = 0.f;
      if (t < 128) {
        float uu = 0.f;
        for (int j = 0; j < 128; j++) uu += G[t * 128 + j] * wcol[j];
        v = uu * wcol[t] + 2.0f * bb[c] * wcol[t] * zsum[t];
      }
      red[t] = v;
      __syncthreads();
      for (int o = 128; o > 0; o >>= 1) { if (t < o) red[t] += red[t + o]; __syncthreads(); }
      if (t == 0) tot += red[0] + 65536.0f * bb[c] * bb[c];
    }
    if (t == 0) atomicAdd(S, tot);
    return;
  }
  {
    __shared__ float wv8[128][8];
    __shared__ float U[128][8];
    __shared__ float zv[8];
    int bi = blk - 130;
    int h = bi >> 4, dg = bi & 15;
    if (t < 128) {
#pragma unroll
      for (int dd = 0; dd < 8; dd++) wv8[t][dd] = Wv[t * 512 + h * 128 + dg * 8 + dd];
    }
    __syncthreads();
    {
      int i = t & 127, du = t >> 7;
      float a0 = 0.f, a1 = 0.f, a2 = 0.f, a3 = 0.f;
      for (int j = 0; j < 128; j++) {
        float gg = G[i * 128 + j];
        a0 += gg * wv8[j][du * 4 + 0]; a1 += gg * wv8[j][du * 4 + 1];
        a2 += gg * wv8[j][du * 4 + 2]; a3 += gg * wv8[j][du * 4 + 3];
      }
      U[i][du * 4 + 0] = a0; U[i][du * 4 + 1] = a1; U[i][du * 4 + 2] = a2; U[i][du * 4 + 3] = a3;
    }
    if (t < 8) {
      float s = 0.f;
      for (int i = 0; i < 128; i++) s += zsum[i] * wv8[i][t];
      zv[t] = s;
    }
    __syncthreads();
    {
      int m = t & 127, du = t >> 7;
      int colk = h * 128 + m;
      float bkm = bk[colk];
      float a[4] = {0.f, 0.f, 0.f, 0.f};
      float wkzs = 0.f;
      for (int i = 0; i < 128; i++) {
        float wk = Wk[i * 512 + colk];
        wkzs += wk * zsum[i];
#pragma unroll
        for (int q = 0; q < 4; q++) a[q] += wk * U[i][du * 4 + q];
      }
#pragma unroll
      for (int q = 0; q < 4; q++) {
        int dd = du * 4 + q;
        int cold = h * 128 + dg * 8 + dd;
        float val = a[q] + wkzs * bv[cold] + bkm * zv[dd] + 65536.0f * bkm * bv[cold];
        kvsT[h * 16384 + (dg * 8 + dd) * 128 + m] = f2b(val);
      }
    }
  }
}

// ---------------------------------------------------------------- prepB: M_h = inv*(Wq_h@kvs_h) + 65536*Wv_h
__global__ __launch_bounds__(256) void k_prepB(const float* __restrict__ Wq, const float* __restrict__ bq,
                                               const float* __restrict__ Wv, const float* __restrict__ bv,
                                               const u16* __restrict__ kvsT, const float* __restrict__ ksum,
                                               const float* __restrict__ SqSk,
                                               u16* __restrict__ Bmat, float* __restrict__ cAv,
                                               u16* __restrict__ U16, float* __restrict__ consts) {
  __shared__ float kvr[8][128];
  int t = threadIdx.x;
  int h = blockIdx.x >> 4, dg = blockIdx.x & 15;
  float inv = rsqrtf(SqSk[0] * SqSk[1]);
  for (int i = t; i < 1024; i += 256) {
    int dl = i >> 7, m = i & 127;
    kvr[dl][m] = b2f(kvsT[h * 16384 + (dg * 8 + dl) * 128 + m]);
  }
  __syncthreads();
  {
    int k = t & 127, du = t >> 7;
    const float* wqr = Wq + k * 512 + h * 128;
    float acc[4] = {0.f, 0.f, 0.f, 0.f};
    for (int m = 0; m < 128; m++) {
      float w = wqr[m];
#pragma unroll
      for (int q = 0; q < 4; q++) acc[q] += w * kvr[du * 4 + q][m];
    }
#pragma unroll
    for (int q = 0; q < 4; q++) {
      int dd = dg * 8 + du * 4 + q;
      float mv = acc[q] * inv + 65536.0f * Wv[k * 512 + h * 128 + dd];
      Bmat[((long)h * 128 + dd) * 128 + k] = f2b(mv);
    }
  }
  if (t < 8) {
    float s = 0.f;
    for (int m = 0; m < 128; m++) s += bq[h * 128 + m] * kvr[t][m];
    cAv[h * 128 + dg * 8 + t] = s * inv + 65536.0f * bv[h * 128 + dg * 8 + t];
  }
  if (dg == 0) {
    if (t < 128) {
      float s = 0.f;
      for (int m = 0; m < 128; m++) s += Wq[t * 512 + h * 128 + m] * ksum[h * 128 + m];
      U16[h * 128 + t] = f2b(s * inv);
    } else if (t == 128) {
      float s = 0.f;
      for (int m = 0; m < 128; m++) s += bq[h * 128 + m] * ksum[h * 128 + m];
      consts[h] = s * inv + 65536.0f;
    }
    if (h == 0) {
      for (int i = t; i < 1536; i += 256) U16[512 + i] = 0;
    }
  }
}

// ---------------------------------------------------------------- mega-fused: attn+LN2+blend -> sg -> enh
// v5 (r8-verified): 256 threads / 4 waves, 32 rows/wave, plain LDS staging.
__global__ __launch_bounds__(256, 2) void k_numfuse(const u16* __restrict__ z0, const u16* __restrict__ gnn,
                                                 const u16* __restrict__ Bmat,
                                                 const float* __restrict__ cAv, const u16* __restrict__ U16,
                                                 const float* __restrict__ consts,
                                                 const float* __restrict__ g2, const float* __restrict__ b2,
                                                 const u16* __restrict__ wsg, const float* __restrict__ sgb,
                                                 u16* __restrict__ enh) {
  __shared__ u16 sA[128 * 132];
  __shared__ u16 sB[128 * 132];
  __shared__ float rden[512];
  __shared__ float caL[512];
  int t = threadIdx.x;
  long n0 = (long)blockIdx.x * 128;
  int wave = t >> 6, lane = t & 63, m = lane & 15, g = lane >> 4;
  u16* myA = sA + wave * 32 * 132;
  {
    const u16* zg = z0 + (n0 + wave * 32) * 128;
#pragma unroll
    for (int i = 0; i < 8; i++) {
      int idx = lane + i * 64;
      *(float4*)(myA + idx * 8 + (idx >> 4) * 4) = *(const float4*)(zg + idx * 8);
    }
  }
  caL[t] = cAv[t]; caL[t + 256] = cAv[t + 256];
  const u16* aB = sA + (wave * 32 + m) * 132 + g * 8;
  short8 a[2][4];
#pragma unroll
  for (int i = 0; i < 2; i++)
#pragma unroll
    for (int s = 0; s < 4; s++) a[i][s] = *(const short8*)(aB + i * 16 * 132 + s * 32);
  {
    f32x4 accd0 = (f32x4){0.f, 0.f, 0.f, 0.f}, accd1 = (f32x4){0.f, 0.f, 0.f, 0.f};
#pragma unroll
    for (int s = 0; s < 4; s++) {
      short8 ub = *(const short8*)(U16 + m * 128 + g * 8 + s * 32);
      accd0 = __builtin_amdgcn_mfma_f32_16x16x32_bf16(a[0][s], ub, accd0, 0, 0, 0);
      accd1 = __builtin_amdgcn_mfma_f32_16x16x32_bf16(a[1][s], ub, accd1, 0, 0, 0);
    }
    if (m < 4) {
      float ch = consts[m];
#pragma unroll
      for (int r = 0; r < 4; r++) {
        rden[(wave * 32 + g * 4 + r) * 4 + m] = 1.0f / (accd0[r] + ch);
        rden[(wave * 32 + 16 + g * 4 + r) * 4 + m] = 1.0f / (accd1[r] + ch);
      }
    }
  }
  f32x4 attn[2][8];
#pragma unroll
  for (int i = 0; i < 2; i++)
#pragma unroll
    for (int c = 0; c < 8; c++) attn[i][c] = (f32x4){0.f, 0.f, 0.f, 0.f};
  for (int h = 0; h < 4; h++) {
    __syncthreads();
    {
      const u16* src = Bmat + (long)h * 16384;
#pragma unroll
      for (int i = 0; i < 8; i++) {
        int idx = t + i * 256;
        *(float4*)(sB + idx * 8 + (idx >> 4) * 4) = *(const float4*)(src + idx * 8);
      }
    }
    __syncthreads();
    f32x4 acc[2][8];
#pragma unroll
    for (int c = 0; c < 8; c++) {
      float ca = caL[h * 128 + c * 16 + m];
      acc[0][c] = (f32x4){ca, ca, ca, ca};
      acc[1][c] = (f32x4){ca, ca, ca, ca};
    }
#pragma unroll
    for (int s = 0; s < 4; s++) {
#pragma unroll
      for (int c = 0; c < 8; c++) {
        short8 bb = *(const short8*)(sB + (c * 16 + m) * 132 + g * 8 + s * 32);
        acc[0][c] = __builtin_amdgcn_mfma_f32_16x16x32_bf16(a[0][s], bb, acc[0][c], 0, 0, 0);
        acc[1][c] = __builtin_amdgcn_mfma_f32_16x16x32_bf16(a[1][s], bb, acc[1][c], 0, 0, 0);
      }
    }
    float rd0[4], rd1[4];
#pragma unroll
    for (int r = 0; r < 4; r++) {
      rd0[r] = rden[(wave * 32 + g * 4 + r) * 4 + h];
      rd1[r] = rden[(wave * 32 + 16 + g * 4 + r) * 4 + h];
    }
#pragma unroll
    for (int c = 0; c < 8; c++)
#pragma unroll
      for (int r = 0; r < 4; r++) {
        attn[0][c][r] += acc[0][c][r] * rd0[r];
        attn[1][c][r] += acc[1][c][r] * rd1[r];
      }
  }
  float4 gv[8];
  {
    const u16* gg = gnn + (n0 + wave * 32) * 128;
#pragma unroll
    for (int i = 0; i < 8; i++) {
      int idx = lane + i * 64;
      gv[i] = *(const float4*)(gg + idx * 8);
    }
  }
  float y[2][8][4];
#pragma unroll
  for (int i = 0; i < 2; i++)
#pragma unroll
    for (int c = 0; c < 8; c++)
#pragma unroll
      for (int r = 0; r < 4; r++)
        y[i][c][r] = 0.125f * attn[i][c][r] + 0.5f * b2f(sA[(wave * 32 + i * 16 + g * 4 + r) * 132 + c * 16 + m]);
  float mu[2][4], rstd[2][4];
#pragma unroll
  for (int i = 0; i < 2; i++)
#pragma unroll
    for (int r = 0; r < 4; r++) {
      float s1 = 0.f, s2 = 0.f;
#pragma unroll
      for (int c = 0; c < 8; c++) { float v = y[i][c][r]; s1 += v; s2 += v * v; }
#pragma unroll
      for (int mask = 1; mask < 16; mask <<= 1) { s1 += __shfl_xor(s1, mask); s2 += __shfl_xor(s2, mask); }
      float mm2 = s1 * (1.f / 128.f);
      mu[i][r] = mm2; rstd[i][r] = rsqrtf(s2 * (1.f / 128.f) - mm2 * mm2 + 1e-5f);
    }
#pragma unroll
  for (int i = 0; i < 8; i++) {
    int idx = lane + i * 64;
    *(float4*)(myA + idx * 8 + (idx >> 4) * 4) = gv[i];
  }
#pragma unroll
  for (int c = 0; c < 8; c++) {
    int d = c * 16 + m;
    float ggc = g2[d], bbc = b2[d];
#pragma unroll
    for (int i = 0; i < 2; i++)
#pragma unroll
      for (int r = 0; r < 4; r++) {
        int loc = (wave * 32 + i * 16 + g * 4 + r) * 132 + d;
        float zr = fmaxf((y[i][c][r] - mu[i][r]) * rstd[i][r] * ggc + bbc, 0.f);
        sA[loc] = f2b(0.8f * b2f(sA[loc]) + 0.2f * zr);
      }
  }
  __syncthreads();
  {
#pragma unroll
    for (int i = 0; i < 8; i++) {
      int idx = t + i * 256;
      *(float4*)(sB + idx * 8 + (idx >> 4) * 4) = *(const float4*)(wsg + idx * 8);
    }
  }
  __syncthreads();
  short8 ap[2][4];
#pragma unroll
  for (int i = 0; i < 2; i++)
#pragma unroll
    for (int s = 0; s < 4; s++) ap[i][s] = *(const short8*)(aB + i * 16 * 132 + s * 32);
  f32x4 acc2[2][8];
#pragma unroll
  for (int c = 0; c < 8; c++) {
    float bc = sgb[c * 16 + m];
    acc2[0][c] = (f32x4){bc, bc, bc, bc};
    acc2[1][c] = (f32x4){bc, bc, bc, bc};
  }
#pragma unroll
  for (int s = 0; s < 4; s++) {
#pragma unroll
    for (int c = 0; c < 8; c++) {
      short8 bb = *(const short8*)(sB + (c * 16 + m) * 132 + g * 8 + s * 32);
      acc2[0][c] = __builtin_amdgcn_mfma_f32_16x16x32_bf16(ap[0][s], bb, acc2[0][c], 0, 0, 0);
      acc2[1][c] = __builtin_amdgcn_mfma_f32_16x16x32_bf16(ap[1][s], bb, acc2[1][c], 0, 0, 0);
    }
  }
#pragma unroll
  for (int i = 0; i < 2; i++)
#pragma unroll
    for (int c = 0; c < 8; c++) {
      int d = c * 16 + m;
#pragma unroll
      for (int r = 0; r < 4; r++)
        enh[(n0 + wave * 32 + i * 16 + g * 4 + r) * 128 + d] = f2b(acc2[i][c][r]);
    }
}

// ---------------------------------------------------------------- k_dec v4: barrier-minimal (4 barriers) + wave-specialized
// r8 analysis: 82% stall on active CUs from ~22 full-block barriers. v4:
// phase A (cur/qd/qt) = wave0 shfl-only; softmax fused per-head single pass
// (waves 0-3); phase D (all projections/LNs/FF/Q-head) = wave0 alone using
// same-wave LDS (lgkmcnt-ordered, no barriers). Waves 1-15 retire after bar4.
__global__ __launch_bounds__(1024) void k_dec(const u16* __restrict__ enh, const int* __restrict__ cidx,
                                             const int* __restrict__ vps,
                                             const float* __restrict__ dWq, const float* __restrict__ dWk,
                                             const float* __restrict__ dWv, const float* __restrict__ dWo,
                                             const float* __restrict__ ln1g, const float* __restrict__ ln1b,
                                             const float* __restrict__ fW1, const float* __restrict__ fb1,
                                             const float* __restrict__ fW2, const float* __restrict__ fb2,
                                             const float* __restrict__ ln2g, const float* __restrict__ ln2b,
                                             const float* __restrict__ qW, const float* __restrict__ qb,
                                             float* __restrict__ out) {
  __shared__ float qtL[4][128];
  __shared__ float scL[4][1024];
  __shared__ float dinvs[4];
  __shared__ float pvL[16][4][128];
  __shared__ float sH[4][128];
  __shared__ float att[128], tn[128], f1[512];
  int b = blockIdx.x, t = threadIdx.x;
  int wave = t >> 6, lane = t & 63;
  const u16* eb = enh + (long)b * 1024 * 128;
  float curr0 = 0.f, curr1 = 0.f;   // wave0: cur[lane], cur[lane+64]
  // ---- A: wave 0 alone (shfl-only, no barriers) ----
  if (wave == 0) {
    int ci = cidx[b];
    const u16* cr = eb + (long)ci * 128;
    curr0 = b2f(cr[lane]);
    curr1 = b2f(cr[lane + 64]);
    float qd0 = 0.f, qd1 = 0.f;
#pragma unroll 16
    for (int k = 0; k < 128; k++) {
      float ck = __shfl((k < 64) ? curr0 : curr1, k & 63);
      qd0 += ck * dWq[k * 128 + lane];
      qd1 += ck * dWq[k * 128 + lane + 64];
    }
#pragma unroll
    for (int h = 0; h < 4; h++) {
      float s0 = 0.f, s1 = 0.f;
#pragma unroll
      for (int c = 0; c < 32; c++) {
        int idx = h * 32 + c;
        float qv = __shfl((idx < 64) ? qd0 : qd1, idx & 63);
        s0 += dWk[lane * 128 + idx] * qv;
        s1 += dWk[(lane + 64) * 128 + idx] * qv;
      }
      qtL[h][lane] = s0;
      qtL[h][lane + 64] = s1;
    }
  }
  __syncthreads();   // bar1: qtL ready
  // ---- B: scores, 1 node/thread ----
  const float scale = 0.17677669529663687f;
  {
    const u16* er = eb + (long)t * 128;
    float s0 = 0.f, s1 = 0.f, s2 = 0.f, s3 = 0.f;
#pragma unroll
    for (int i8 = 0; i8 < 16; i8++) {
      short8 ev = *(const short8*)(er + i8 * 8);
#pragma unroll
      for (int j = 0; j < 8; j++) {
        float e = b2f((u16)ev[j]);
        int k = i8 * 8 + j;
        s0 += e * qtL[0][k]; s1 += e * qtL[1][k]; s2 += e * qtL[2][k]; s3 += e * qtL[3][k];
      }
    }
    scL[0][t] = s0 * scale; scL[1][t] = s1 * scale; scL[2][t] = s2 * scale; scL[3][t] = s3 * scale;
  }
  __syncthreads();   // bar2: scores ready
  // ---- softmax: waves 0-3, one head each, single fused pass ----
  if (wave < 4) {
    float v[16];
    float mx = -3.0e38f;
#pragma unroll
    for (int i = 0; i < 16; i++) { v[i] = scL[wave][lane + i * 64]; mx = fmaxf(mx, v[i]); }
#pragma unroll
    for (int msk = 1; msk < 64; msk <<= 1) mx = fmaxf(mx, __shfl_xor(mx, msk));
    float sm = 0.f;
#pragma unroll
    for (int i = 0; i < 16; i++) { float e = __expf(v[i] - mx); scL[wave][lane + i * 64] = e; sm += e; }
#pragma unroll
    for (int msk = 1; msk < 64; msk <<= 1) sm += __shfl_xor(sm, msk);
    if (lane == 0) dinvs[wave] = 1.0f / sm;
  }
  __syncthreads();   // bar3: softmax ready
  // ---- C: PV, 64 parts x 16 nodes ----
  {
    int seg = t & 15, part = t >> 4;
    float acc[4][8];
#pragma unroll
    for (int h = 0; h < 4; h++)
#pragma unroll
      for (int j = 0; j < 8; j++) acc[h][j] = 0.f;
    for (int i = 0; i < 16; i++) {
      int n = part * 16 + i;
      short8 e8 = *(const short8*)(eb + (long)n * 128 + seg * 8);
      float p0 = scL[0][n], p1 = scL[1][n], p2 = scL[2][n], p3 = scL[3][n];
#pragma unroll
      for (int j = 0; j < 8; j++) {
        float e = b2f((u16)e8[j]);
        acc[0][j] += p0 * e; acc[1][j] += p1 * e; acc[2][j] += p2 * e; acc[3][j] += p3 * e;
      }
    }
#pragma unroll
    for (int h = 0; h < 4; h++)
#pragma unroll
      for (int j = 0; j < 8; j++) {
        acc[h][j] += __shfl_xor(acc[h][j], 16);
        acc[h][j] += __shfl_xor(acc[h][j], 32);
      }
    if (lane < 16) {
#pragma unroll
      for (int h = 0; h < 4; h++)
#pragma unroll
        for (int j = 0; j < 8; j++) pvL[wave][h][seg * 8 + j] = acc[h][j];
    }
  }
  __syncthreads();   // bar4: pvL ready
  if (wave != 0) return;
  // ---- D: wave 0 alone; same-wave LDS is lgkmcnt-ordered, no barriers ----
  // sH reduce
#pragma unroll
  for (int h = 0; h < 4; h++)
#pragma unroll
    for (int d2 = 0; d2 < 2; d2++) {
      int d = d2 * 64 + lane;
      float s = 0.f;
#pragma unroll
      for (int w = 0; w < 16; w++) s += pvL[w][h][d];
      sH[h][d] = s;
    }
  // att = (sH @ dWv per head) * dinv
#pragma unroll
  for (int o2 = 0; o2 < 2; o2++) {
    int o = o2 * 64 + lane;
    int h = o >> 5, e = o & 31;
    float s = 0.f;
    for (int k = 0; k < 128; k++) s += sH[h][k] * dWv[k * 128 + h * 32 + e];
    att[o] = s * dinvs[h];
  }
  // tv = cur + att @ dWo ; LN1
  float tvr[2];
#pragma unroll
  for (int o2 = 0; o2 < 2; o2++) {
    int o = o2 * 64 + lane;
    float s = 0.f;
    for (int k = 0; k < 128; k++) s += att[k] * dWo[k * 128 + o];
    tvr[o2] = (o2 == 0 ? curr0 : curr1) + s;
  }
  {
    float s1 = tvr[0] + tvr[1], s2 = tvr[0] * tvr[0] + tvr[1] * tvr[1];
#pragma unroll
    for (int msk = 1; msk < 64; msk <<= 1) { s1 += __shfl_xor(s1, msk); s2 += __shfl_xor(s2, msk); }
    float mm = s1 * (1.f / 128.f);
    float rs = rsqrtf(s2 * (1.f / 128.f) - mm * mm + 1e-5f);
#pragma unroll
    for (int o2 = 0; o2 < 2; o2++) {
      int o = o2 * 64 + lane;
      tn[o] = (tvr[o2] - mm) * rs * ln1g[o] + ln1b[o];
    }
  }
  // FF1: 8 consecutive outputs per lane (float4 weight loads)
  {
    float sacc[8];
    int c0 = lane * 8;
#pragma unroll
    for (int j = 0; j < 8; j++) sacc[j] = fb1[c0 + j];
    for (int k = 0; k < 128; k++) {
      float tk = tn[k];
      float4 w0 = *(const float4*)(fW1 + k * 512 + c0);
      float4 w1 = *(const float4*)(fW1 + k * 512 + c0 + 4);
      sacc[0] += tk * w0.x; sacc[1] += tk * w0.y; sacc[2] += tk * w0.z; sacc[3] += tk * w0.w;
      sacc[4] += tk * w1.x; sacc[5] += tk * w1.y; sacc[6] += tk * w1.z; sacc[7] += tk * w1.w;
    }
#pragma unroll
    for (int j = 0; j < 8; j++) f1[c0 + j] = fmaxf(sacc[j], 0.0f);
  }
  // FF2 (o = lane*2+j, float2 weight loads) + LN2 + base + vp
  float glb[2];
  {
    float s0 = 0.f, s1 = 0.f;
    int o0 = lane * 2;
    for (int k = 0; k < 512; k++) {
      float fk = f1[k];
      float2 w = *(const float2*)(fW2 + k * 128 + o0);
      s0 += fk * w.x; s1 += fk * w.y;
    }
    float tv20 = tn[o0] + s0 + fb2[o0];
    float tv21 = tn[o0 + 1] + s1 + fb2[o0 + 1];
    float s1r = tv20 + tv21, s2r = tv20 * tv20 + tv21 * tv21;
#pragma unroll
    for (int msk = 1; msk < 64; msk <<= 1) { s1r += __shfl_xor(s1r, msk); s2r += __shfl_xor(s2r, msk); }
    float mm = s1r * (1.f / 128.f);
    float rs = rsqrtf(s2r * (1.f / 128.f) - mm * mm + 1e-5f);
    glb[0] = (tv20 - mm) * rs * ln2g[o0] + ln2b[o0];
    glb[1] = (tv21 - mm) * rs * ln2g[o0 + 1] + ln2b[o0 + 1];
  }
  float base;
  {
    int o0 = lane * 2;
    float p = glb[0] * qW[o0] + glb[1] * qW[o0 + 1]
            + curr0 * qW[128 + lane] + curr1 * qW[128 + lane + 64];
#pragma unroll
    for (int msk = 1; msk < 64; msk <<= 1) p += __shfl_xor(p, msk);
    base = p + qb[0];
  }
#pragma unroll
  for (int o2 = 0; o2 < 2; o2++) {
    int o = lane * 2 + o2;
    int vi = vps[b * 128 + o];
    const u16* er = eb + (long)vi * 128;
    float s = 0.f;
#pragma unroll
    for (int i8 = 0; i8 < 16; i8++) {
      short8 ev = *(const short8*)(er + i8 * 8);
#pragma unroll
      for (int j = 0; j < 8; j++) s += b2f((u16)ev[j]) * qW[256 + i8 * 8 + j];
    }
    out[b * 128 + o] = base + s;
  }
}

// ================================================================ launch
extern "C" void kernel_launch(void* const* d_in, const int* in_sizes, int n_in,
                              void* d_out, int out_size, void* d_ws, size_t ws_size,
                              hipStream_t stream) {
  const float* node_in = (const float*)d_in[0];
  const int* cur_idx   = (const int*)d_in[2];
  const int* vps       = (const int*)d_in[3];
  const int* adj       = (const int*)d_in[5];
  const float* W_init  = (const float*)d_in[6];
  const float* b_init  = (const float*)d_in[7];
  const float* gcn_W   = (const float*)d_in[8];
  const float* gcn_b   = (const float*)d_in[9];
  const float* tc_fc_W = (const float*)d_in[10];
  const float* tc_fc_b = (const float*)d_in[11];
  const float* ln1g    = (const float*)d_in[12];
  const float* ln1b    = (const float*)d_in[13];
  const float* Wq      = (const float*)d_in[14];
  const float* bq      = (const float*)d_in[15];
  const float* Wk      = (const float*)d_in[16];
  const float* bk      = (const float*)d_in[17];
  const float* Wv      = (const float*)d_in[18];
  const float* bv      = (const float*)d_in[19];
  const float* ln2g    = (const float*)d_in[20];
  const float* ln2b    = (const float*)d_in[21];
  const float* sg_W    = (const float*)d_in[22];
  const float* sg_b    = (const float*)d_in[23];
  const float* dWq     = (const float*)d_in[24];
  const float* dWk     = (const float*)d_in[25];
  const float* dWv     = (const float*)d_in[26];
  const float* dWo     = (const float*)d_in[27];
  const float* dln1g   = (const float*)d_in[28];
  const float* dln1b   = (const float*)d_in[29];
  const float* fW1     = (const float*)d_in[30];
  const float* fb1     = (const float*)d_in[31];
  const float* fW2     = (const float*)d_in[32];
  const float* fb2     = (const float*)d_in[33];
  const float* dln2g   = (const float*)d_in[34];
  const float* dln2b   = (const float*)d_in[35];
  const float* qW      = (const float*)d_in[36];
  const float* qb      = (const float*)d_in[37];

  char* base = (char*)d_ws;
  u16* bufA = (u16*)base;                           // x0 -> gcn ping -> gnn
  u16* bufB = (u16*)(base + 16777216);              // z0 -> enh
  u16* bufC = (u16*)(base + 33554432);              // gcn temp
  u16* z0T  = (u16*)(base + 50331648);              // [128][BN]
  float* Gpart = (float*)(base + 67108864);         // [128][16384]
  char* sm = base + 83886080;
  u16* kvsT   = (u16*)sm;                           // 65536 u16
  u16* wts    = (u16*)(sm + 131072);                // 327680 u16
  float* bqkv = (float*)(sm + 131072 + 655360);     // 1536 (unused slot)
  float* ksum = bqkv + 1536;                        // 512
  float* SqSk = ksum + 512;                         // 2
  float* zsum = SqSk + 2;                           // 128
  float* Gm   = zsum + 128;                         // 16384
  float* dinv = Gm + 16384;                         // 65536
  float* cAv  = dinv + BNn;                         // 512
  float* consts = cAv + 512;                        // 4
  u16* Bmat = (u16*)(consts + 4);                   // 65536 u16
  u16* U16m = Bmat + 65536;                         // 2048 u16

  // prep + embed + deg + zero (merged)
  k_init<<<2089, 256, 0, stream>>>(gcn_W, tc_fc_W, sg_W, dWk, dWv, Wq, Wk, Wv,
                                   node_in, W_init, b_init, adj, dinv, wts, SqSk, bufA);

  // z0 = relu(LN(x0 @ tc_fc + b)) -> bufB (+ z0T)
  k_gemm<2><<<512, 256, 0, stream>>>(bufA, wts + 4 * 16384, tc_fc_b, ln1g, ln1b, bufB, z0T);

  // Gram chain -> analytic stats/kvs -> merged M matrices
  k_gram<<<128, 256, 0, stream>>>(z0T, Gpart, zsum);
  k_gram_red<<<64, 256, 0, stream>>>(Gpart, Gm);
  k_statskvs<<<194, 256, 0, stream>>>(Wq, bq, Wk, bk, Wv, bv, Gm, zsum, ksum, SqSk, SqSk + 1, kvsT);
  k_prepB<<<64, 256, 0, stream>>>(Wq, bq, Wv, bv, kvsT, ksum, SqSk, Bmat, cAv, U16m, consts);

  // fused GCN x4 (XCD-locality swizzle; v2 batched gather)
  k_gcn<<<1024, 256, 0, stream>>>(bufA, wts + 0 * 16384, adj, dinv, gcn_b + 0, bufC, 1);
  k_gcn<<<1024, 256, 0, stream>>>(bufC, wts + 1 * 16384, adj, dinv, gcn_b + 128, bufA, 1);
  k_gcn<<<1024, 256, 0, stream>>>(bufA, wts + 2 * 16384, adj, dinv, gcn_b + 256, bufC, 1);
  k_gcn<<<1024, 256, 0, stream>>>(bufC, wts + 3 * 16384, adj, dinv, gcn_b + 384, bufA, 0);  // gnn -> bufA

  // mega-fused attention combine + sg -> enh (v5)
  k_numfuse<<<512, 256, 0, stream>>>(bufB, bufA, Bmat, cAv, U16m, consts, ln2g, ln2b,
                                     wts + 5 * 16384, sg_b, bufB);

  // fused decoder v4: 4 barriers, wave-specialized tail
  k_dec<<<64, 1024, 0, stream>>>(bufB, cur_idx, vps, dWq, dWk, dWv, dWo, dln1g, dln1b,
                                 fW1, fb1, fW2, fb2, dln2g, dln2b, qW, qb, (float*)d_out);
}

// Round 10
// 442.254 us; speedup vs baseline: 1.0031x; 1.0031x over previous
//
#include <hip/hip_runtime.h>

#define BNn 65536L   // B*N

typedef unsigned short u16;
typedef unsigned int u32;
typedef __attribute__((ext_vector_type(8))) short short8;
typedef __attribute__((ext_vector_type(4))) float f32x4;

__device__ inline u16 f2b(float f){ u32 u = __float_as_uint(f); u32 r = (u + 0x7fffu + ((u>>16)&1u))>>16; return (u16)r; }
__device__ inline float b2f(u16 b){ return __uint_as_float(((u32)b)<<16); }

// ---------------------------------------------------------------- init: blocks 0..40 weight prep (+zero), 41.. embed (+deg)
__global__ __launch_bounds__(256) void k_init(const float* __restrict__ gcnW, const float* __restrict__ tcW,
                       const float* __restrict__ sgW, const float* __restrict__ dKW,
                       const float* __restrict__ dVW,
                       const float* __restrict__ Wq, const float* __restrict__ Wk, const float* __restrict__ Wv,
                       const float* __restrict__ in, const float* __restrict__ Wi, const float* __restrict__ bi,
                       const int* __restrict__ adj, float* __restrict__ dinv,
                       u16* __restrict__ wts, float* __restrict__ SqSkz, u16* __restrict__ x0) {
  __shared__ u16 sT[64 * 136];
  __shared__ float Ws[1024];
  __shared__ float bs[128];
  __shared__ float ins[256];
  int bid = blockIdx.x, t = threadIdx.x;
  if (bid < 41) {
    if (bid == 40) {
      if (t < 130) SqSkz[t] = 0.0f;   // Sq, Sk, zsum
      return;
    }
    const float* src; long dst; int lds_src;
    if (bid < 16) {
      int mtx = bid >> 1, kh = bid & 1;
      src = (mtx < 4 ? gcnW + mtx * 16384 : mtx == 4 ? tcW : mtx == 5 ? sgW : mtx == 6 ? dKW : dVW) + kh * 64 * 128;
      dst = (long)mtx * 16384 + kh * 64;
      lds_src = 128;
    } else {
      int q = bid - 16; int mat = q >> 3, rem = q & 7, kh = rem >> 2, cb = rem & 3;
      src = (mat == 0 ? Wq : mat == 1 ? Wk : Wv) + kh * 64 * 512 + cb * 128;
      dst = 131072L + (long)(mat * 512 + cb * 128) * 128 + kh * 64;
      lds_src = 512;
    }
#pragma unroll
    for (int i = 0; i < 32; i++) {
      int idx = t + i * 256; int row = idx >> 7, col = idx & 127;
      sT[row * 136 + col] = f2b(src[(long)row * lds_src + col]);
    }
    __syncthreads();
    {
      int n = t >> 1, kb = t & 1;
      u16 ob[32];
#pragma unroll
      for (int k = 0; k < 32; k++) ob[k] = sT[(kb * 32 + k) * 136 + n];
      uint4* o4 = (uint4*)(wts + dst + (long)n * 128 + kb * 32);
      uint4* s4 = (uint4*)ob;
#pragma unroll
      for (int k = 0; k < 4; k++) o4[k] = s4[k];
    }
    return;
  }
  int b = bid - 41;   // 0..2047
  long row0 = (long)b * 32;
  if (b < 256) {
    int n = b * 256 + t;
    int cnt = 0;
#pragma unroll
    for (int j = 0; j < 16; j++) cnt += (adj[(long)n * 16 + j] >= 0) ? 1 : 0;
    dinv[n] = rsqrtf((float)cnt + 1.0f);
  }
#pragma unroll
  for (int i = 0; i < 4; i++) Ws[t + i * 256] = Wi[t + i * 256];
  if (t < 128) bs[t] = bi[t];
  ins[t] = in[row0 * 8 + t];
  __syncthreads();
  int row = t >> 3, seg = t & 7;
  float acc[16];
#pragma unroll
  for (int i = 0; i < 16; i++) acc[i] = bs[seg * 16 + i];
#pragma unroll
  for (int k = 0; k < 8; k++) {
    float f = ins[row * 8 + k];
#pragma unroll
    for (int i = 0; i < 16; i++) acc[i] += f * Ws[k * 128 + seg * 16 + i];
  }
  u16 ob[16];
#pragma unroll
  for (int i = 0; i < 16; i++) ob[i] = f2b(acc[i]);
  uint4* o4 = (uint4*)(x0 + (row0 + row) * 128 + seg * 16);
  uint4* s4 = (uint4*)ob;
  o4[0] = s4[0]; o4[1] = s4[1];
}

// ---------------------------------------------------------------- MFMA GEMM: 128 rows/block, W in LDS, A in regs
template<int EPI>
__global__ __launch_bounds__(256) void k_gemm(const u16* __restrict__ A,
                                              const u16* __restrict__ WT,
                                              const float* __restrict__ bias,
                                              const float* __restrict__ lng,
                                              const float* __restrict__ lnb,
                                              u16* __restrict__ C,
                                              u16* __restrict__ CT) {
  __shared__ u16 sW[128 * 136];
  int t = threadIdx.x;
  long row0 = (long)blockIdx.x * 128;
  int wave = t >> 6, lane = t & 63, m = lane & 15, g = lane >> 4;
#pragma unroll
  for (int i = 0; i < 8; i++) {
    int idx = t + i * 256; int row = idx >> 4, ch = idx & 15;
    *(float4*)(sW + row * 136 + ch * 8) = *(const float4*)(WT + row * 128 + ch * 8);
  }
  short8 a[2][4];
#pragma unroll
  for (int i = 0; i < 2; i++) {
    const u16* aG = A + (row0 + wave * 32 + i * 16 + m) * 128 + g * 8;
#pragma unroll
    for (int s = 0; s < 4; s++) a[i][s] = *(const short8*)(aG + s * 32);
  }
  __syncthreads();
  f32x4 acc[2][8];
#pragma unroll
  for (int i = 0; i < 2; i++)
#pragma unroll
    for (int c = 0; c < 8; c++) acc[i][c] = (f32x4){0.f, 0.f, 0.f, 0.f};
#pragma unroll
  for (int s = 0; s < 4; s++) {
#pragma unroll
    for (int c = 0; c < 8; c++) {
      short8 bb = *(const short8*)(sW + (c * 16 + m) * 136 + g * 8 + s * 32);
      acc[0][c] = __builtin_amdgcn_mfma_f32_16x16x32_bf16(a[0][s], bb, acc[0][c], 0, 0, 0);
      acc[1][c] = __builtin_amdgcn_mfma_f32_16x16x32_bf16(a[1][s], bb, acc[1][c], 0, 0, 0);
    }
  }
#pragma unroll
  for (int c = 0; c < 8; c++) {
    float bc = bias ? bias[c * 16 + m] : 0.0f;
#pragma unroll
    for (int i = 0; i < 2; i++)
#pragma unroll
      for (int r = 0; r < 4; r++) acc[i][c][r] += bc;
  }
  if (EPI == 2) {
    float gg[8], bb2[8];
#pragma unroll
    for (int c = 0; c < 8; c++) { gg[c] = lng[c * 16 + m]; bb2[c] = lnb[c * 16 + m]; }
#pragma unroll
    for (int i = 0; i < 2; i++)
#pragma unroll
      for (int r = 0; r < 4; r++) {
        float s1 = 0.f, s2 = 0.f;
#pragma unroll
        for (int c = 0; c < 8; c++) { float y = acc[i][c][r]; s1 += y; s2 += y * y; }
#pragma unroll
        for (int mask = 1; mask < 16; mask <<= 1) { s1 += __shfl_xor(s1, mask); s2 += __shfl_xor(s2, mask); }
        float mu = s1 * (1.f / 128.f);
        float rstd = rsqrtf(s2 * (1.f / 128.f) - mu * mu + 1e-5f);
#pragma unroll
        for (int c = 0; c < 8; c++)
          acc[i][c][r] = fmaxf((acc[i][c][r] - mu) * rstd * gg[c] + bb2[c], 0.f);
      }
  }
#pragma unroll
  for (int i = 0; i < 2; i++) {
    long rb = row0 + wave * 32 + i * 16 + g * 4;
#pragma unroll
    for (int c = 0; c < 8; c++) {
      int col = c * 16 + m;
      u16 ob[4];
#pragma unroll
      for (int r = 0; r < 4; r++) {
        float y = acc[i][c][r];
        if (EPI == 1) y = fmaxf(y, 0.f);
        ob[r] = f2b(y);
        C[(rb + r) * 128 + col] = ob[r];
      }
      if (CT) {
        uint2 p;
        p.x = ((u32)ob[1] << 16) | ob[0]; p.y = ((u32)ob[3] << 16) | ob[2];
        *(uint2*)(CT + (long)col * BNn + rb) = p;
      }
    }
  }
}

// ---------------------------------------------------------------- fused GCN layer: 256 threads, 64 rows/block, XCD swizzle
// v2: neighbor gather batched 4-at-a-time (16 uint4 in flight) for MLP depth.
__global__ __launch_bounds__(256) void k_gcn(const u16* __restrict__ h,
                                             const u16* __restrict__ WT,
                                             const int* __restrict__ adj,
                                             const float* __restrict__ dinv,
                                             const float* __restrict__ gb,
                                             u16* __restrict__ out, int relu) {
  __shared__ u16 sA[64 * 132];
  __shared__ u16 sW[128 * 132];
  int t = threadIdx.x;
  int lane = t & 63;
  int p = blockIdx.x;
  long n0 = ((long)(p & 63) << 10) + ((long)(p >> 6) << 6);   // graph*1024 + tile*64
#pragma unroll
  for (int i = 0; i < 8; i++) {
    int idx = t + i * 256; int row = idx >> 4, ch = idx & 15;
    *(float4*)(sW + row * 132 + ch * 8) = *(const float4*)(WT + row * 128 + ch * 8);
  }
  {
    int row = t >> 2, seg = t & 3;
    long n = n0 + row;
    float din = dinv[n];
    float d2v = din * din;
    int4 a4 = *(const int4*)(adj + n * 16 + seg * 4);
    int cols[4]; float enq[4];
    int bb = ((int)(n >> 10)) << 10;
    const int* ap = &a4.x;
#pragma unroll
    for (int q = 0; q < 4; q++) {
      int a = ap[q];
      int valid = a >= 0;
      int cc = (valid ? a : 0) + bb;
      cols[q] = cc;
      enq[q] = valid ? din * dinv[cc] : 0.0f;
    }
    float acc[32];
    {
      const u16* hr = h + n * 128 + seg * 32;
      uint4 v0 = *(const uint4*)(hr), v1 = *(const uint4*)(hr + 8), v2 = *(const uint4*)(hr + 16), v3 = *(const uint4*)(hr + 24);
      const u16* pv = (const u16*)&v0;
#pragma unroll
      for (int i = 0; i < 8; i++) acc[i] = b2f(pv[i]) * d2v;
      pv = (const u16*)&v1;
#pragma unroll
      for (int i = 0; i < 8; i++) acc[8 + i] = b2f(pv[i]) * d2v;
      pv = (const u16*)&v2;
#pragma unroll
      for (int i = 0; i < 8; i++) acc[16 + i] = b2f(pv[i]) * d2v;
      pv = (const u16*)&v3;
#pragma unroll
      for (int i = 0; i < 8; i++) acc[24 + i] = b2f(pv[i]) * d2v;
    }
#pragma unroll
    for (int jb = 0; jb < 4; jb++) {
      int cc4[4]; float e4[4];
      uint4 nv[16];
#pragma unroll
      for (int q = 0; q < 4; q++) {
        int j = jb * 4 + q;
        int src = (lane & 60) | (j >> 2);
        cc4[q] = __shfl(cols[j & 3], src);
        e4[q] = __shfl(enq[j & 3], src);
        const u16* nb = h + (long)cc4[q] * 128 + seg * 32;
        nv[q * 4 + 0] = *(const uint4*)(nb);
        nv[q * 4 + 1] = *(const uint4*)(nb + 8);
        nv[q * 4 + 2] = *(const uint4*)(nb + 16);
        nv[q * 4 + 3] = *(const uint4*)(nb + 24);
      }
#pragma unroll
      for (int q = 0; q < 4; q++) {
        float e = e4[q];
#pragma unroll
        for (int v = 0; v < 4; v++) {
          const u16* pv = (const u16*)&nv[q * 4 + v];
#pragma unroll
          for (int i = 0; i < 8; i++) acc[v * 8 + i] += e * b2f(pv[i]);
        }
      }
    }
    u16 ob[32];
#pragma unroll
    for (int i = 0; i < 32; i++) ob[i] = f2b(acc[i]);
    uint4* o4 = (uint4*)(sA + row * 132 + seg * 32);
    uint4* s4 = (uint4*)ob;
#pragma unroll
    for (int i = 0; i < 4; i++) o4[i] = s4[i];
  }
  __syncthreads();
  int wave = t >> 6, m = lane & 15, g = lane >> 4;
  const u16* aB = sA + (wave * 16 + m) * 132 + g * 8;
  short8 a[4];
#pragma unroll
  for (int s = 0; s < 4; s++) a[s] = *(const short8*)(aB + s * 32);
  f32x4 acc[8];
#pragma unroll
  for (int c = 0; c < 8; c++) {
    float bc = gb[c * 16 + m];
    acc[c] = (f32x4){bc, bc, bc, bc};
  }
#pragma unroll
  for (int s = 0; s < 4; s++) {
#pragma unroll
    for (int c = 0; c < 8; c++) {
      short8 bb = *(const short8*)(sW + (c * 16 + m) * 132 + g * 8 + s * 32);
      acc[c] = __builtin_amdgcn_mfma_f32_16x16x32_bf16(a[s], bb, acc[c], 0, 0, 0);
    }
  }
#pragma unroll
  for (int c = 0; c < 8; c++) {
    int col = c * 16 + m;
#pragma unroll
    for (int r = 0; r < 4; r++) {
      float y = acc[c][r];
      if (relu) y = fmaxf(y, 0.f);
      out[(n0 + wave * 16 + g * 4 + r) * 128 + col] = f2b(y);
    }
  }
}

// ---------------------------------------------------------------- Gram: 2 slices/block, Gpart[128], + zsum
__global__ __launch_bounds__(256) void k_gram(const u16* __restrict__ z0T,
                                              float* __restrict__ Gpart, float* __restrict__ zsum) {
  __shared__ u16 sZT[128 * 264];
  int t = threadIdx.x;
  int wave = t >> 6, lane = t & 63, m = lane & 15, g = lane >> 4;
  f32x4 acc[2][8];
#pragma unroll
  for (int i = 0; i < 2; i++)
#pragma unroll
    for (int c = 0; c < 8; c++) acc[i][c] = (f32x4){0.f, 0.f, 0.f, 0.f};
  float zs = 0.f;
  for (int sl = 0; sl < 2; sl++) {
    long k0 = (long)(blockIdx.x * 2 + sl) * 256;
    __syncthreads();
#pragma unroll
    for (int i = 0; i < 16; i++) {
      int idx = t + i * 256; int mm = idx >> 5, ch = idx & 31;
      *(float4*)(sZT + mm * 264 + ch * 8) = *(const float4*)(z0T + (long)mm * BNn + k0 + ch * 8);
    }
    __syncthreads();
#pragma unroll
    for (int kk = 0; kk < 8; kk++) {
      short8 a0 = *(const short8*)(sZT + (wave * 32 + m) * 264 + kk * 32 + g * 8);
      short8 a1 = *(const short8*)(sZT + (wave * 32 + 16 + m) * 264 + kk * 32 + g * 8);
#pragma unroll
      for (int c = 0; c < 8; c++) {
        short8 bb = *(const short8*)(sZT + (c * 16 + m) * 264 + kk * 32 + g * 8);
        acc[0][c] = __builtin_amdgcn_mfma_f32_16x16x32_bf16(a0, bb, acc[0][c], 0, 0, 0);
        acc[1][c] = __builtin_amdgcn_mfma_f32_16x16x32_bf16(a1, bb, acc[1][c], 0, 0, 0);
      }
    }
    if (t < 128) {
      float s = 0.f;
      for (int j = 0; j < 256; j++) s += b2f(sZT[t * 264 + j]);
      zs += s;
    }
  }
  if (t < 128) atomicAdd(&zsum[t], zs);
  float* P = Gpart + (long)blockIdx.x * 16384 + wave * 4096;
#pragma unroll
  for (int i = 0; i < 2; i++)
#pragma unroll
    for (int c = 0; c < 8; c++)
      *(f32x4*)(P + (i * 8 + c) * 256 + lane * 4) = acc[i][c];
}

// ---------------------------------------------------------------- reduce Gram partials -> G fp32 [128][128]
__global__ void k_gram_red(const float* __restrict__ Gpart, float* __restrict__ G) {
  int o = blockIdx.x * 256 + threadIdx.x;   // 0..16383
  float s = 0.f;
  for (int b = 0; b < 128; b++) s += Gpart[(long)b * 16384 + o];
  int wave = o >> 12, rem = o & 4095;
  int ic = rem >> 8, i = ic >> 3, c = ic & 7;
  int rem2 = rem & 255, lane = rem2 >> 2, q = rem2 & 3;
  int m = lane & 15, g = lane >> 4;
  int mi = wave * 32 + i * 16 + g * 4 + q;
  int mj = c * 16 + m;
  G[mi * 128 + mj] = s;
}

// ---------------------------------------------------------------- merged stats + kvsT
__global__ __launch_bounds__(256) void k_statskvs(const float* __restrict__ Wq, const float* __restrict__ bq,
                                                  const float* __restrict__ Wk, const float* __restrict__ bk,
                                                  const float* __restrict__ Wv, const float* __restrict__ bv,
                                                  const float* __restrict__ G, const float* __restrict__ zsum,
                                                  float* __restrict__ ksum,
                                                  float* __restrict__ Sq, float* __restrict__ Sk,
                                                  u16* __restrict__ kvsT) {
  int t = threadIdx.x;
  int blk = blockIdx.x;
  if (blk < 2) {
    int c = blk * 256 + t;
    float s = 0.f;
    for (int i = 0; i < 128; i++) s += Wk[i * 512 + c] * zsum[i];
    ksum[c] = s + 65536.0f * bk[c];
    return;
  }
  if (blk < 130) {
    __shared__ float wcol[128];
    __shared__ float red[256];
    int bi = blk - 2;
    int isK = bi >> 6;
    const float* W = isK ? Wk : Wq;
    const float* bb = isK ? bk : bq;
    float* S = isK ? Sk : Sq;
    int c0 = (bi & 63) * 8;
    float tot = 0.f;
    for (int cc = 0; cc < 8; cc++) {
      int c = c0 + cc;
      __syncthreads();
      if (t < 128) wcol[t] = W[t * 512 + c];
      __syncthreads();
      float v = 0.f;
      if (t < 128) {
        float uu = 0.f;
        for (int j = 0; j < 128; j++) uu += G[t * 128 + j] * wcol[j];
        v = uu * wcol[t] + 2.0f * bb[c] * wcol[t] * zsum[t];
      }
      red[t] = v;
      __syncthreads();
      for (int o = 128; o > 0; o >>= 1) { if (t < o) red[t] += red[t + o]; __syncthreads(); }
      if (t == 0) tot += red[0] + 65536.0f * bb[c] * bb[c];
    }
    if (t == 0) atomicAdd(S, tot);
    return;
  }
  {
    __shared__ float wv8[128][8];
    __shared__ float U[128][8];
    __shared__ float zv[8];
    int bi = blk - 130;
    int h = bi >> 4, dg = bi & 15;
    if (t < 128) {
#pragma unroll
      for (int dd = 0; dd < 8; dd++) wv8[t][dd] = Wv[t * 512 + h * 128 + dg * 8 + dd];
    }
    __syncthreads();
    {
      int i = t & 127, du = t >> 7;
      float a0 = 0.f, a1 = 0.f, a2 = 0.f, a3 = 0.f;
      for (int j = 0; j < 128; j++) {
        float gg = G[i * 128 + j];
        a0 += gg * wv8[j][du * 4 + 0]; a1 += gg * wv8[j][du * 4 + 1];
        a2 += gg * wv8[j][du * 4 + 2]; a3 += gg * wv8[j][du * 4 + 3];
      }
      U[i][du * 4 + 0] = a0; U[i][du * 4 + 1] = a1; U[i][du * 4 + 2] = a2; U[i][du * 4 + 3] = a3;
    }
    if (t < 8) {
      float s = 0.f;
      for (int i = 0; i < 128; i++) s += zsum[i] * wv8[i][t];
      zv[t] = s;
    }
    __syncthreads();
    {
      int m = t & 127, du = t >> 7;
      int colk = h * 128 + m;
      float bkm = bk[colk];
      float a[4] = {0.f, 0.f, 0.f, 0.f};
      float wkzs = 0.f;
      for (int i = 0; i < 128; i++) {
        float wk = Wk[i * 512 + colk];
        wkzs += wk * zsum[i];
#pragma unroll
        for (int q = 0; q < 4; q++) a[q] += wk * U[i][du * 4 + q];
      }
#pragma unroll
      for (int q = 0; q < 4; q++) {
        int dd = du * 4 + q;
        int cold = h * 128 + dg * 8 + dd;
        float val = a[q] + wkzs * bv[cold] + bkm * zv[dd] + 65536.0f * bkm * bv[cold];
        kvsT[h * 16384 + (dg * 8 + dd) * 128 + m] = f2b(val);
      }
    }
  }
}

// ---------------------------------------------------------------- prepB: M_h = inv*(Wq_h@kvs_h) + 65536*Wv_h
__global__ __launch_bounds__(256) void k_prepB(const float* __restrict__ Wq, const float* __restrict__ bq,
                                               const float* __restrict__ Wv, const float* __restrict__ bv,
                                               const u16* __restrict__ kvsT, const float* __restrict__ ksum,
                                               const float* __restrict__ SqSk,
                                               u16* __restrict__ Bmat, float* __restrict__ cAv,
                                               u16* __restrict__ U16, float* __restrict__ consts) {
  __shared__ float kvr[8][128];
  int t = threadIdx.x;
  int h = blockIdx.x >> 4, dg = blockIdx.x & 15;
  float inv = rsqrtf(SqSk[0] * SqSk[1]);
  for (int i = t; i < 1024; i += 256) {
    int dl = i >> 7, m = i & 127;
    kvr[dl][m] = b2f(kvsT[h * 16384 + (dg * 8 + dl) * 128 + m]);
  }
  __syncthreads();
  {
    int k = t & 127, du = t >> 7;
    const float* wqr = Wq + k * 512 + h * 128;
    float acc[4] = {0.f, 0.f, 0.f, 0.f};
    for (int m = 0; m < 128; m++) {
      float w = wqr[m];
#pragma unroll
      for (int q = 0; q < 4; q++) acc[q] += w * kvr[du * 4 + q][m];
    }
#pragma unroll
    for (int q = 0; q < 4; q++) {
      int dd = dg * 8 + du * 4 + q;
      float mv = acc[q] * inv + 65536.0f * Wv[k * 512 + h * 128 + dd];
      Bmat[((long)h * 128 + dd) * 128 + k] = f2b(mv);
    }
  }
  if (t < 8) {
    float s = 0.f;
    for (int m = 0; m < 128; m++) s += bq[h * 128 + m] * kvr[t][m];
    cAv[h * 128 + dg * 8 + t] = s * inv + 65536.0f * bv[h * 128 + dg * 8 + t];
  }
  if (dg == 0) {
    if (t < 128) {
      float s = 0.f;
      for (int m = 0; m < 128; m++) s += Wq[t * 512 + h * 128 + m] * ksum[h * 128 + m];
      U16[h * 128 + t] = f2b(s * inv);
    } else if (t == 128) {
      float s = 0.f;
      for (int m = 0; m < 128; m++) s += bq[h * 128 + m] * ksum[h * 128 + m];
      consts[h] = s * inv + 65536.0f;
    }
    if (h == 0) {
      for (int i = t; i < 1536; i += 256) U16[512 + i] = 0;
    }
  }
}

// ---------------------------------------------------------------- mega-fused: attn+LN2+blend -> sg -> enh
// v5 (r8-verified): 256 threads / 4 waves, 32 rows/wave, plain LDS staging.
__global__ __launch_bounds__(256, 2) void k_numfuse(const u16* __restrict__ z0, const u16* __restrict__ gnn,
                                                 const u16* __restrict__ Bmat,
                                                 const float* __restrict__ cAv, const u16* __restrict__ U16,
                                                 const float* __restrict__ consts,
                                                 const float* __restrict__ g2, const float* __restrict__ b2,
                                                 const u16* __restrict__ wsg, const float* __restrict__ sgb,
                                                 u16* __restrict__ enh) {
  __shared__ u16 sA[128 * 132];
  __shared__ u16 sB[128 * 132];
  __shared__ float rden[512];
  __shared__ float caL[512];
  int t = threadIdx.x;
  long n0 = (long)blockIdx.x * 128;
  int wave = t >> 6, lane = t & 63, m = lane & 15, g = lane >> 4;
  u16* myA = sA + wave * 32 * 132;
  {
    const u16* zg = z0 + (n0 + wave * 32) * 128;
#pragma unroll
    for (int i = 0; i < 8; i++) {
      int idx = lane + i * 64;
      *(float4*)(myA + idx * 8 + (idx >> 4) * 4) = *(const float4*)(zg + idx * 8);
    }
  }
  caL[t] = cAv[t]; caL[t + 256] = cAv[t + 256];
  const u16* aB = sA + (wave * 32 + m) * 132 + g * 8;
  short8 a[2][4];
#pragma unroll
  for (int i = 0; i < 2; i++)
#pragma unroll
    for (int s = 0; s < 4; s++) a[i][s] = *(const short8*)(aB + i * 16 * 132 + s * 32);
  {
    f32x4 accd0 = (f32x4){0.f, 0.f, 0.f, 0.f}, accd1 = (f32x4){0.f, 0.f, 0.f, 0.f};
#pragma unroll
    for (int s = 0; s < 4; s++) {
      short8 ub = *(const short8*)(U16 + m * 128 + g * 8 + s * 32);
      accd0 = __builtin_amdgcn_mfma_f32_16x16x32_bf16(a[0][s], ub, accd0, 0, 0, 0);
      accd1 = __builtin_amdgcn_mfma_f32_16x16x32_bf16(a[1][s], ub, accd1, 0, 0, 0);
    }
    if (m < 4) {
      float ch = consts[m];
#pragma unroll
      for (int r = 0; r < 4; r++) {
        rden[(wave * 32 + g * 4 + r) * 4 + m] = 1.0f / (accd0[r] + ch);
        rden[(wave * 32 + 16 + g * 4 + r) * 4 + m] = 1.0f / (accd1[r] + ch);
      }
    }
  }
  f32x4 attn[2][8];
#pragma unroll
  for (int i = 0; i < 2; i++)
#pragma unroll
    for (int c = 0; c < 8; c++) attn[i][c] = (f32x4){0.f, 0.f, 0.f, 0.f};
  for (int h = 0; h < 4; h++) {
    __syncthreads();
    {
      const u16* src = Bmat + (long)h * 16384;
#pragma unroll
      for (int i = 0; i < 8; i++) {
        int idx = t + i * 256;
        *(float4*)(sB + idx * 8 + (idx >> 4) * 4) = *(const float4*)(src + idx * 8);
      }
    }
    __syncthreads();
    f32x4 acc[2][8];
#pragma unroll
    for (int c = 0; c < 8; c++) {
      float ca = caL[h * 128 + c * 16 + m];
      acc[0][c] = (f32x4){ca, ca, ca, ca};
      acc[1][c] = (f32x4){ca, ca, ca, ca};
    }
#pragma unroll
    for (int s = 0; s < 4; s++) {
#pragma unroll
      for (int c = 0; c < 8; c++) {
        short8 bb = *(const short8*)(sB + (c * 16 + m) * 132 + g * 8 + s * 32);
        acc[0][c] = __builtin_amdgcn_mfma_f32_16x16x32_bf16(a[0][s], bb, acc[0][c], 0, 0, 0);
        acc[1][c] = __builtin_amdgcn_mfma_f32_16x16x32_bf16(a[1][s], bb, acc[1][c], 0, 0, 0);
      }
    }
    float rd0[4], rd1[4];
#pragma unroll
    for (int r = 0; r < 4; r++) {
      rd0[r] = rden[(wave * 32 + g * 4 + r) * 4 + h];
      rd1[r] = rden[(wave * 32 + 16 + g * 4 + r) * 4 + h];
    }
#pragma unroll
    for (int c = 0; c < 8; c++)
#pragma unroll
      for (int r = 0; r < 4; r++) {
        attn[0][c][r] += acc[0][c][r] * rd0[r];
        attn[1][c][r] += acc[1][c][r] * rd1[r];
      }
  }
  float4 gv[8];
  {
    const u16* gg = gnn + (n0 + wave * 32) * 128;
#pragma unroll
    for (int i = 0; i < 8; i++) {
      int idx = lane + i * 64;
      gv[i] = *(const float4*)(gg + idx * 8);
    }
  }
  float y[2][8][4];
#pragma unroll
  for (int i = 0; i < 2; i++)
#pragma unroll
    for (int c = 0; c < 8; c++)
#pragma unroll
      for (int r = 0; r < 4; r++)
        y[i][c][r] = 0.125f * attn[i][c][r] + 0.5f * b2f(sA[(wave * 32 + i * 16 + g * 4 + r) * 132 + c * 16 + m]);
  float mu[2][4], rstd[2][4];
#pragma unroll
  for (int i = 0; i < 2; i++)
#pragma unroll
    for (int r = 0; r < 4; r++) {
      float s1 = 0.f, s2 = 0.f;
#pragma unroll
      for (int c = 0; c < 8; c++) { float v = y[i][c][r]; s1 += v; s2 += v * v; }
#pragma unroll
      for (int mask = 1; mask < 16; mask <<= 1) { s1 += __shfl_xor(s1, mask); s2 += __shfl_xor(s2, mask); }
      float mm2 = s1 * (1.f / 128.f);
      mu[i][r] = mm2; rstd[i][r] = rsqrtf(s2 * (1.f / 128.f) - mm2 * mm2 + 1e-5f);
    }
#pragma unroll
  for (int i = 0; i < 8; i++) {
    int idx = lane + i * 64;
    *(float4*)(myA + idx * 8 + (idx >> 4) * 4) = gv[i];
  }
#pragma unroll
  for (int c = 0; c < 8; c++) {
    int d = c * 16 + m;
    float ggc = g2[d], bbc = b2[d];
#pragma unroll
    for (int i = 0; i < 2; i++)
#pragma unroll
      for (int r = 0; r < 4; r++) {
        int loc = (wave * 32 + i * 16 + g * 4 + r) * 132 + d;
        float zr = fmaxf((y[i][c][r] - mu[i][r]) * rstd[i][r] * ggc + bbc, 0.f);
        sA[loc] = f2b(0.8f * b2f(sA[loc]) + 0.2f * zr);
      }
  }
  __syncthreads();
  {
#pragma unroll
    for (int i = 0; i < 8; i++) {
      int idx = t + i * 256;
      *(float4*)(sB + idx * 8 + (idx >> 4) * 4) = *(const float4*)(wsg + idx * 8);
    }
  }
  __syncthreads();
  short8 ap[2][4];
#pragma unroll
  for (int i = 0; i < 2; i++)
#pragma unroll
    for (int s = 0; s < 4; s++) ap[i][s] = *(const short8*)(aB + i * 16 * 132 + s * 32);
  f32x4 acc2[2][8];
#pragma unroll
  for (int c = 0; c < 8; c++) {
    float bc = sgb[c * 16 + m];
    acc2[0][c] = (f32x4){bc, bc, bc, bc};
    acc2[1][c] = (f32x4){bc, bc, bc, bc};
  }
#pragma unroll
  for (int s = 0; s < 4; s++) {
#pragma unroll
    for (int c = 0; c < 8; c++) {
      short8 bb = *(const short8*)(sB + (c * 16 + m) * 132 + g * 8 + s * 32);
      acc2[0][c] = __builtin_amdgcn_mfma_f32_16x16x32_bf16(ap[0][s], bb, acc2[0][c], 0, 0, 0);
      acc2[1][c] = __builtin_amdgcn_mfma_f32_16x16x32_bf16(ap[1][s], bb, acc2[1][c], 0, 0, 0);
    }
  }
#pragma unroll
  for (int i = 0; i < 2; i++)
#pragma unroll
    for (int c = 0; c < 8; c++) {
      int d = c * 16 + m;
#pragma unroll
      for (int r = 0; r < 4; r++)
        enh[(n0 + wave * 32 + i * 16 + g * 4 + r) * 128 + d] = f2b(acc2[i][c][r]);
    }
}

// ---------------------------------------------------------------- k_dec v5: v2 body (measured best 59.4us) with the
// 3-barrier softmax replaced by v4's verified fused single-pass version
// (waves 0-3 do max+exp+sum in regs; saves 2 full-block barriers).
__global__ __launch_bounds__(1024) void k_dec(const u16* __restrict__ enh, const int* __restrict__ cidx,
                                             const int* __restrict__ vps,
                                             const float* __restrict__ dWq, const float* __restrict__ dWk,
                                             const float* __restrict__ dWv, const float* __restrict__ dWo,
                                             const float* __restrict__ ln1g, const float* __restrict__ ln1b,
                                             const float* __restrict__ fW1, const float* __restrict__ fb1,
                                             const float* __restrict__ fW2, const float* __restrict__ fb2,
                                             const float* __restrict__ ln2g, const float* __restrict__ ln2b,
                                             const float* __restrict__ qW, const float* __restrict__ qb,
                                             float* __restrict__ out) {
  __shared__ float cur[128], qd[128], qtL[4][128];
  __shared__ float scL[4][1024];
  __shared__ float dinvs[4];
  __shared__ float pvL[16][4][128];
  __shared__ float sH[4][128];
  __shared__ float att[128], tn[128], tv[128], f1[512], glob[128];
  __shared__ float red[16], red2[16];
  __shared__ float mu_s, rs_s, base_s;
  int b = blockIdx.x, t = threadIdx.x;
  int wave = t >> 6, lane = t & 63;
  const u16* eb = enh + (long)b * 1024 * 128;
  if (t < 128) cur[t] = b2f(eb[(long)cidx[b] * 128 + t]);
  __syncthreads();
  {
    int o = t >> 3, p = t & 7;
    float s = 0.f;
    int k0 = p * 16;
#pragma unroll
    for (int k = 0; k < 16; k++) s += cur[k0 + k] * dWq[(k0 + k) * 128 + o];
    s += __shfl_xor(s, 1); s += __shfl_xor(s, 2); s += __shfl_xor(s, 4);
    if (p == 0) qd[o] = s;
  }
  __syncthreads();
  if (t < 512) {
    int h = t >> 7, col = t & 127;
    float s = 0.f;
#pragma unroll
    for (int c = 0; c < 32; c++) s += dWk[col * 128 + h * 32 + c] * qd[h * 32 + c];
    qtL[h][col] = s;
  }
  __syncthreads();
  const float scale = 0.17677669529663687f;
  {
    const u16* er = eb + (long)t * 128;
    float s0 = 0.f, s1 = 0.f, s2 = 0.f, s3 = 0.f;
#pragma unroll
    for (int i8 = 0; i8 < 16; i8++) {
      short8 ev = *(const short8*)(er + i8 * 8);
#pragma unroll
      for (int j = 0; j < 8; j++) {
        float e = b2f((u16)ev[j]);
        int k = i8 * 8 + j;
        s0 += e * qtL[0][k]; s1 += e * qtL[1][k]; s2 += e * qtL[2][k]; s3 += e * qtL[3][k];
      }
    }
    scL[0][t] = s0 * scale; scL[1][t] = s1 * scale; scL[2][t] = s2 * scale; scL[3][t] = s3 * scale;
  }
  __syncthreads();
  // fused softmax (verified in v4): waves 0-3, one head each, single pass
  if (wave < 4) {
    float v[16];
    float mx = -3.0e38f;
#pragma unroll
    for (int i = 0; i < 16; i++) { v[i] = scL[wave][lane + i * 64]; mx = fmaxf(mx, v[i]); }
#pragma unroll
    for (int msk = 1; msk < 64; msk <<= 1) mx = fmaxf(mx, __shfl_xor(mx, msk));
    float sm = 0.f;
#pragma unroll
    for (int i = 0; i < 16; i++) { float e = __expf(v[i] - mx); scL[wave][lane + i * 64] = e; sm += e; }
#pragma unroll
    for (int msk = 1; msk < 64; msk <<= 1) sm += __shfl_xor(sm, msk);
    if (lane == 0) dinvs[wave] = 1.0f / sm;
  }
  __syncthreads();
  {
    int seg = t & 15, part = t >> 4;
    float acc[4][8];
#pragma unroll
    for (int h = 0; h < 4; h++)
#pragma unroll
      for (int j = 0; j < 8; j++) acc[h][j] = 0.f;
    for (int i = 0; i < 16; i++) {
      int n = part * 16 + i;
      short8 e8 = *(const short8*)(eb + (long)n * 128 + seg * 8);
      float p0 = scL[0][n], p1 = scL[1][n], p2 = scL[2][n], p3 = scL[3][n];
#pragma unroll
      for (int j = 0; j < 8; j++) {
        float e = b2f((u16)e8[j]);
        acc[0][j] += p0 * e; acc[1][j] += p1 * e; acc[2][j] += p2 * e; acc[3][j] += p3 * e;
      }
    }
#pragma unroll
    for (int h = 0; h < 4; h++)
#pragma unroll
      for (int j = 0; j < 8; j++) {
        acc[h][j] += __shfl_xor(acc[h][j], 16);
        acc[h][j] += __shfl_xor(acc[h][j], 32);
      }
    if (lane < 16) {
#pragma unroll
      for (int h = 0; h < 4; h++)
#pragma unroll
        for (int j = 0; j < 8; j++) pvL[wave][h][seg * 8 + j] = acc[h][j];
    }
  }
  __syncthreads();
  if (t < 512) {
    int h = t >> 7, d = t & 127;
    float s = 0.f;
#pragma unroll
    for (int w = 0; w < 16; w++) s += pvL[w][h][d];
    sH[h][d] = s;
  }
  __syncthreads();
  {
    int o = t >> 3, p = t & 7;
    int h = o >> 5, e = o & 31;
    float s = 0.f;
    int k0 = p * 16;
#pragma unroll
    for (int k = 0; k < 16; k++) s += sH[h][k0 + k] * dWv[(k0 + k) * 128 + h * 32 + e];
    s += __shfl_xor(s, 1); s += __shfl_xor(s, 2); s += __shfl_xor(s, 4);
    if (p == 0) att[o] = s * dinvs[h];
  }
  __syncthreads();
  {
    int o = t >> 3, p = t & 7;
    float s = 0.f;
    int k0 = p * 16;
#pragma unroll
    for (int k = 0; k < 16; k++) s += att[k0 + k] * dWo[(k0 + k) * 128 + o];
    s += __shfl_xor(s, 1); s += __shfl_xor(s, 2); s += __shfl_xor(s, 4);
    if (p == 0) tv[o] = cur[o] + s;
  }
  __syncthreads();
  {
    float v = (t < 128) ? tv[t] : 0.f;
    float s1 = v, s2 = v * v;
#pragma unroll
    for (int msk = 1; msk < 64; msk <<= 1) { s1 += __shfl_xor(s1, msk); s2 += __shfl_xor(s2, msk); }
    if (lane == 0) { red[wave] = s1; red2[wave] = s2; }
  }
  __syncthreads();
  if (t == 0) {
    float s1 = 0.f, s2 = 0.f;
#pragma unroll
    for (int w = 0; w < 16; w++) { s1 += red[w]; s2 += red2[w]; }
    float mm = s1 / 128.0f;
    mu_s = mm; rs_s = rsqrtf(s2 / 128.0f - mm * mm + 1e-5f);
  }
  __syncthreads();
  if (t < 128) tn[t] = (tv[t] - mu_s) * rs_s * ln1g[t] + ln1b[t];
  __syncthreads();
  if (t < 512) {
    float s = fb1[t];
    for (int k = 0; k < 128; k++) s += tn[k] * fW1[k * 512 + t];
    f1[t] = fmaxf(s, 0.0f);
  }
  __syncthreads();
  {
    int o = t >> 3, p = t & 7;
    float s = 0.f;
    int k0 = p * 64;
#pragma unroll
    for (int k = 0; k < 64; k++) s += f1[k0 + k] * fW2[(k0 + k) * 128 + o];
    s += __shfl_xor(s, 1); s += __shfl_xor(s, 2); s += __shfl_xor(s, 4);
    if (p == 0) tv[o] = tn[o] + s + fb2[o];
  }
  __syncthreads();
  {
    float v = (t < 128) ? tv[t] : 0.f;
    float s1 = v, s2 = v * v;
#pragma unroll
    for (int msk = 1; msk < 64; msk <<= 1) { s1 += __shfl_xor(s1, msk); s2 += __shfl_xor(s2, msk); }
    if (lane == 0) { red[wave] = s1; red2[wave] = s2; }
  }
  __syncthreads();
  if (t == 0) {
    float s1 = 0.f, s2 = 0.f;
#pragma unroll
    for (int w = 0; w < 16; w++) { s1 += red[w]; s2 += red2[w]; }
    float mm = s1 / 128.0f;
    mu_s = mm; rs_s = rsqrtf(s2 / 128.0f - mm * mm + 1e-5f);
  }
  __syncthreads();
  if (t < 128) glob[t] = (tv[t] - mu_s) * rs_s * ln2g[t] + ln2b[t];
  __syncthreads();
  {
    float v = 0.f;
    if (t < 256) v = (t < 128 ? glob[t] : cur[t - 128]) * qW[t];
    float s = v;
#pragma unroll
    for (int msk = 1; msk < 64; msk <<= 1) s += __shfl_xor(s, msk);
    if (lane == 0) red[wave] = s;
  }
  __syncthreads();
  if (t == 0) {
    float s = 0.f;
#pragma unroll
    for (int w = 0; w < 16; w++) s += red[w];
    base_s = s + qb[0];
  }
  __syncthreads();
  {
    int o = t >> 3, p = t & 7;
    int vi = vps[b * 128 + o];
    const u16* er = eb + (long)vi * 128 + p * 16;
    short8 e0 = *(const short8*)(er);
    short8 e1 = *(const short8*)(er + 8);
    float s = 0.f;
#pragma unroll
    for (int j = 0; j < 8; j++) {
      s += b2f((u16)e0[j]) * qW[256 + p * 16 + j];
      s += b2f((u16)e1[j]) * qW[256 + p * 16 + 8 + j];
    }
    s += __shfl_xor(s, 1); s += __shfl_xor(s, 2); s += __shfl_xor(s, 4);
    if (p == 0) out[b * 128 + o] = base_s + s;
  }
}

// ================================================================ launch
extern "C" void kernel_launch(void* const* d_in, const int* in_sizes, int n_in,
                              void* d_out, int out_size, void* d_ws, size_t ws_size,
                              hipStream_t stream) {
  const float* node_in = (const float*)d_in[0];
  const int* cur_idx   = (const int*)d_in[2];
  const int* vps       = (const int*)d_in[3];
  const int* adj       = (const int*)d_in[5];
  const float* W_init  = (const float*)d_in[6];
  const float* b_init  = (const float*)d_in[7];
  const float* gcn_W   = (const float*)d_in[8];
  const float* gcn_b   = (const float*)d_in[9];
  const float* tc_fc_W = (const float*)d_in[10];
  const float* tc_fc_b = (const float*)d_in[11];
  const float* ln1g    = (const float*)d_in[12];
  const float* ln1b    = (const float*)d_in[13];
  const float* Wq      = (const float*)d_in[14];
  const float* bq      = (const float*)d_in[15];
  const float* Wk      = (const float*)d_in[16];
  const float* bk      = (const float*)d_in[17];
  const float* Wv      = (const float*)d_in[18];
  const float* bv      = (const float*)d_in[19];
  const float* ln2g    = (const float*)d_in[20];
  const float* ln2b    = (const float*)d_in[21];
  const float* sg_W    = (const float*)d_in[22];
  const float* sg_b    = (const float*)d_in[23];
  const float* dWq     = (const float*)d_in[24];
  const float* dWk     = (const float*)d_in[25];
  const float* dWv     = (const float*)d_in[26];
  const float* dWo     = (const float*)d_in[27];
  const float* dln1g   = (const float*)d_in[28];
  const float* dln1b   = (const float*)d_in[29];
  const float* fW1     = (const float*)d_in[30];
  const float* fb1     = (const float*)d_in[31];
  const float* fW2     = (const float*)d_in[32];
  const float* fb2     = (const float*)d_in[33];
  const float* dln2g   = (const float*)d_in[34];
  const float* dln2b   = (const float*)d_in[35];
  const float* qW      = (const float*)d_in[36];
  const float* qb      = (const float*)d_in[37];

  char* base = (char*)d_ws;
  u16* bufA = (u16*)base;                           // x0 -> gcn ping -> gnn
  u16* bufB = (u16*)(base + 16777216);              // z0 -> enh
  u16* bufC = (u16*)(base + 33554432);              // gcn temp
  u16* z0T  = (u16*)(base + 50331648);              // [128][BN]
  float* Gpart = (float*)(base + 67108864);         // [128][16384]
  char* sm = base + 83886080;
  u16* kvsT   = (u16*)sm;                           // 65536 u16
  u16* wts    = (u16*)(sm + 131072);                // 327680 u16
  float* bqkv = (float*)(sm + 131072 + 655360);     // 1536 (unused slot)
  float* ksum = bqkv + 1536;                        // 512
  float* SqSk = ksum + 512;                         // 2
  float* zsum = SqSk + 2;                           // 128
  float* Gm   = zsum + 128;                         // 16384
  float* dinv = Gm + 16384;                         // 65536
  float* cAv  = dinv + BNn;                         // 512
  float* consts = cAv + 512;                        // 4
  u16* Bmat = (u16*)(consts + 4);                   // 65536 u16
  u16* U16m = Bmat + 65536;                         // 2048 u16

  // prep + embed + deg + zero (merged)
  k_init<<<2089, 256, 0, stream>>>(gcn_W, tc_fc_W, sg_W, dWk, dWv, Wq, Wk, Wv,
                                   node_in, W_init, b_init, adj, dinv, wts, SqSk, bufA);

  // z0 = relu(LN(x0 @ tc_fc + b)) -> bufB (+ z0T)
  k_gemm<2><<<512, 256, 0, stream>>>(bufA, wts + 4 * 16384, tc_fc_b, ln1g, ln1b, bufB, z0T);

  // Gram chain -> analytic stats/kvs -> merged M matrices
  k_gram<<<128, 256, 0, stream>>>(z0T, Gpart, zsum);
  k_gram_red<<<64, 256, 0, stream>>>(Gpart, Gm);
  k_statskvs<<<194, 256, 0, stream>>>(Wq, bq, Wk, bk, Wv, bv, Gm, zsum, ksum, SqSk, SqSk + 1, kvsT);
  k_prepB<<<64, 256, 0, stream>>>(Wq, bq, Wv, bv, kvsT, ksum, SqSk, Bmat, cAv, U16m, consts);

  // fused GCN x4 (XCD-locality swizzle; v2 batched gather)
  k_gcn<<<1024, 256, 0, stream>>>(bufA, wts + 0 * 16384, adj, dinv, gcn_b + 0, bufC, 1);
  k_gcn<<<1024, 256, 0, stream>>>(bufC, wts + 1 * 16384, adj, dinv, gcn_b + 128, bufA, 1);
  k_gcn<<<1024, 256, 0, stream>>>(bufA, wts + 2 * 16384, adj, dinv, gcn_b + 256, bufC, 1);
  k_gcn<<<1024, 256, 0, stream>>>(bufC, wts + 3 * 16384, adj, dinv, gcn_b + 384, bufA, 0);  // gnn -> bufA

  // mega-fused attention combine + sg -> enh (v5)
  k_numfuse<<<512, 256, 0, stream>>>(bufB, bufA, Bmat, cAv, U16m, consts, ln2g, ln2b,
                                     wts + 5 * 16384, sg_b, bufB);

  // fused decoder v5 (v2 + fused softmax)
  k_dec<<<64, 1024, 0, stream>>>(bufB, cur_idx, vps, dWq, dWk, dWv, dWo, dln1g, dln1b,
                                 fW1, fb1, fW2, fb2, dln2g, dln2b, qW, qb, (float*)d_out);
}

// Round 12
// 436.479 us; speedup vs baseline: 1.0164x; 1.0132x over previous
//
#include <hip/hip_runtime.h>

#define BNn 65536L   // B*N

typedef unsigned short u16;
typedef unsigned int u32;
typedef __attribute__((ext_vector_type(8))) short short8;
typedef __attribute__((ext_vector_type(4))) float f32x4;

__device__ inline u16 f2b(float f){ u32 u = __float_as_uint(f); u32 r = (u + 0x7fffu + ((u>>16)&1u))>>16; return (u16)r; }
__device__ inline float b2f(u16 b){ return __uint_as_float(((u32)b)<<16); }

// ---------------------------------------------------------------- init: blocks 0..40 weight prep (+zero), 41.. embed (+deg)
__global__ __launch_bounds__(256) void k_init(const float* __restrict__ gcnW, const float* __restrict__ tcW,
                       const float* __restrict__ sgW, const float* __restrict__ dKW,
                       const float* __restrict__ dVW,
                       const float* __restrict__ Wq, const float* __restrict__ Wk, const float* __restrict__ Wv,
                       const float* __restrict__ in, const float* __restrict__ Wi, const float* __restrict__ bi,
                       const int* __restrict__ adj, float* __restrict__ dinv,
                       u16* __restrict__ wts, float* __restrict__ SqSkz, u16* __restrict__ x0) {
  __shared__ u16 sT[64 * 136];
  __shared__ float Ws[1024];
  __shared__ float bs[128];
  __shared__ float ins[256];
  int bid = blockIdx.x, t = threadIdx.x;
  if (bid < 41) {
    if (bid == 40) {
      if (t < 130) SqSkz[t] = 0.0f;   // Sq, Sk, zsum
      return;
    }
    const float* src; long dst; int lds_src;
    if (bid < 16) {
      int mtx = bid >> 1, kh = bid & 1;
      src = (mtx < 4 ? gcnW + mtx * 16384 : mtx == 4 ? tcW : mtx == 5 ? sgW : mtx == 6 ? dKW : dVW) + kh * 64 * 128;
      dst = (long)mtx * 16384 + kh * 64;
      lds_src = 128;
    } else {
      int q = bid - 16; int mat = q >> 3, rem = q & 7, kh = rem >> 2, cb = rem & 3;
      src = (mat == 0 ? Wq : mat == 1 ? Wk : Wv) + kh * 64 * 512 + cb * 128;
      dst = 131072L + (long)(mat * 512 + cb * 128) * 128 + kh * 64;
      lds_src = 512;
    }
#pragma unroll
    for (int i = 0; i < 32; i++) {
      int idx = t + i * 256; int row = idx >> 7, col = idx & 127;
      sT[row * 136 + col] = f2b(src[(long)row * lds_src + col]);
    }
    __syncthreads();
    {
      int n = t >> 1, kb = t & 1;
      u16 ob[32];
#pragma unroll
      for (int k = 0; k < 32; k++) ob[k] = sT[(kb * 32 + k) * 136 + n];
      uint4* o4 = (uint4*)(wts + dst + (long)n * 128 + kb * 32);
      uint4* s4 = (uint4*)ob;
#pragma unroll
      for (int k = 0; k < 4; k++) o4[k] = s4[k];
    }
    return;
  }
  int b = bid - 41;   // 0..2047
  long row0 = (long)b * 32;
  if (b < 256) {
    int n = b * 256 + t;
    int cnt = 0;
#pragma unroll
    for (int j = 0; j < 16; j++) cnt += (adj[(long)n * 16 + j] >= 0) ? 1 : 0;
    dinv[n] = rsqrtf((float)cnt + 1.0f);
  }
#pragma unroll
  for (int i = 0; i < 4; i++) Ws[t + i * 256] = Wi[t + i * 256];
  if (t < 128) bs[t] = bi[t];
  ins[t] = in[row0 * 8 + t];
  __syncthreads();
  int row = t >> 3, seg = t & 7;
  float acc[16];
#pragma unroll
  for (int i = 0; i < 16; i++) acc[i] = bs[seg * 16 + i];
#pragma unroll
  for (int k = 0; k < 8; k++) {
    float f = ins[row * 8 + k];
#pragma unroll
    for (int i = 0; i < 16; i++) acc[i] += f * Ws[k * 128 + seg * 16 + i];
  }
  u16 ob[16];
#pragma unroll
  for (int i = 0; i < 16; i++) ob[i] = f2b(acc[i]);
  uint4* o4 = (uint4*)(x0 + (row0 + row) * 128 + seg * 16);
  uint4* s4 = (uint4*)ob;
  o4[0] = s4[0]; o4[1] = s4[1];
}

// ---------------------------------------------------------------- MFMA GEMM: 128 rows/block, W in LDS, A in regs
template<int EPI>
__global__ __launch_bounds__(256) void k_gemm(const u16* __restrict__ A,
                                              const u16* __restrict__ WT,
                                              const float* __restrict__ bias,
                                              const float* __restrict__ lng,
                                              const float* __restrict__ lnb,
                                              u16* __restrict__ C,
                                              u16* __restrict__ CT) {
  __shared__ u16 sW[128 * 136];
  int t = threadIdx.x;
  long row0 = (long)blockIdx.x * 128;
  int wave = t >> 6, lane = t & 63, m = lane & 15, g = lane >> 4;
#pragma unroll
  for (int i = 0; i < 8; i++) {
    int idx = t + i * 256; int row = idx >> 4, ch = idx & 15;
    *(float4*)(sW + row * 136 + ch * 8) = *(const float4*)(WT + row * 128 + ch * 8);
  }
  short8 a[2][4];
#pragma unroll
  for (int i = 0; i < 2; i++) {
    const u16* aG = A + (row0 + wave * 32 + i * 16 + m) * 128 + g * 8;
#pragma unroll
    for (int s = 0; s < 4; s++) a[i][s] = *(const short8*)(aG + s * 32);
  }
  __syncthreads();
  f32x4 acc[2][8];
#pragma unroll
  for (int i = 0; i < 2; i++)
#pragma unroll
    for (int c = 0; c < 8; c++) acc[i][c] = (f32x4){0.f, 0.f, 0.f, 0.f};
#pragma unroll
  for (int s = 0; s < 4; s++) {
#pragma unroll
    for (int c = 0; c < 8; c++) {
      short8 bb = *(const short8*)(sW + (c * 16 + m) * 136 + g * 8 + s * 32);
      acc[0][c] = __builtin_amdgcn_mfma_f32_16x16x32_bf16(a[0][s], bb, acc[0][c], 0, 0, 0);
      acc[1][c] = __builtin_amdgcn_mfma_f32_16x16x32_bf16(a[1][s], bb, acc[1][c], 0, 0, 0);
    }
  }
#pragma unroll
  for (int c = 0; c < 8; c++) {
    float bc = bias ? bias[c * 16 + m] : 0.0f;
#pragma unroll
    for (int i = 0; i < 2; i++)
#pragma unroll
      for (int r = 0; r < 4; r++) acc[i][c][r] += bc;
  }
  if (EPI == 2) {
    float gg[8], bb2[8];
#pragma unroll
    for (int c = 0; c < 8; c++) { gg[c] = lng[c * 16 + m]; bb2[c] = lnb[c * 16 + m]; }
#pragma unroll
    for (int i = 0; i < 2; i++)
#pragma unroll
      for (int r = 0; r < 4; r++) {
        float s1 = 0.f, s2 = 0.f;
#pragma unroll
        for (int c = 0; c < 8; c++) { float y = acc[i][c][r]; s1 += y; s2 += y * y; }
#pragma unroll
        for (int mask = 1; mask < 16; mask <<= 1) { s1 += __shfl_xor(s1, mask); s2 += __shfl_xor(s2, mask); }
        float mu = s1 * (1.f / 128.f);
        float rstd = rsqrtf(s2 * (1.f / 128.f) - mu * mu + 1e-5f);
#pragma unroll
        for (int c = 0; c < 8; c++)
          acc[i][c][r] = fmaxf((acc[i][c][r] - mu) * rstd * gg[c] + bb2[c], 0.f);
      }
  }
#pragma unroll
  for (int i = 0; i < 2; i++) {
    long rb = row0 + wave * 32 + i * 16 + g * 4;
#pragma unroll
    for (int c = 0; c < 8; c++) {
      int col = c * 16 + m;
      u16 ob[4];
#pragma unroll
      for (int r = 0; r < 4; r++) {
        float y = acc[i][c][r];
        if (EPI == 1) y = fmaxf(y, 0.f);
        ob[r] = f2b(y);
        C[(rb + r) * 128 + col] = ob[r];
      }
      if (CT) {
        uint2 p;
        p.x = ((u32)ob[1] << 16) | ob[0]; p.y = ((u32)ob[3] << 16) | ob[2];
        *(uint2*)(CT + (long)col * BNn + rb) = p;
      }
    }
  }
}

// ---------------------------------------------------------------- fused GCN layer: 256 threads, 64 rows/block, XCD swizzle
// v2: neighbor gather batched 4-at-a-time (16 uint4 in flight) for MLP depth.
__global__ __launch_bounds__(256) void k_gcn(const u16* __restrict__ h,
                                             const u16* __restrict__ WT,
                                             const int* __restrict__ adj,
                                             const float* __restrict__ dinv,
                                             const float* __restrict__ gb,
                                             u16* __restrict__ out, int relu) {
  __shared__ u16 sA[64 * 132];
  __shared__ u16 sW[128 * 132];
  int t = threadIdx.x;
  int lane = t & 63;
  int p = blockIdx.x;
  long n0 = ((long)(p & 63) << 10) + ((long)(p >> 6) << 6);   // graph*1024 + tile*64
#pragma unroll
  for (int i = 0; i < 8; i++) {
    int idx = t + i * 256; int row = idx >> 4, ch = idx & 15;
    *(float4*)(sW + row * 132 + ch * 8) = *(const float4*)(WT + row * 128 + ch * 8);
  }
  {
    int row = t >> 2, seg = t & 3;
    long n = n0 + row;
    float din = dinv[n];
    float d2v = din * din;
    int4 a4 = *(const int4*)(adj + n * 16 + seg * 4);
    int cols[4]; float enq[4];
    int bb = ((int)(n >> 10)) << 10;
    const int* ap = &a4.x;
#pragma unroll
    for (int q = 0; q < 4; q++) {
      int a = ap[q];
      int valid = a >= 0;
      int cc = (valid ? a : 0) + bb;
      cols[q] = cc;
      enq[q] = valid ? din * dinv[cc] : 0.0f;
    }
    float acc[32];
    {
      const u16* hr = h + n * 128 + seg * 32;
      uint4 v0 = *(const uint4*)(hr), v1 = *(const uint4*)(hr + 8), v2 = *(const uint4*)(hr + 16), v3 = *(const uint4*)(hr + 24);
      const u16* pv = (const u16*)&v0;
#pragma unroll
      for (int i = 0; i < 8; i++) acc[i] = b2f(pv[i]) * d2v;
      pv = (const u16*)&v1;
#pragma unroll
      for (int i = 0; i < 8; i++) acc[8 + i] = b2f(pv[i]) * d2v;
      pv = (const u16*)&v2;
#pragma unroll
      for (int i = 0; i < 8; i++) acc[16 + i] = b2f(pv[i]) * d2v;
      pv = (const u16*)&v3;
#pragma unroll
      for (int i = 0; i < 8; i++) acc[24 + i] = b2f(pv[i]) * d2v;
    }
#pragma unroll
    for (int jb = 0; jb < 4; jb++) {
      int cc4[4]; float e4[4];
      uint4 nv[16];
#pragma unroll
      for (int q = 0; q < 4; q++) {
        int j = jb * 4 + q;
        int src = (lane & 60) | (j >> 2);
        cc4[q] = __shfl(cols[j & 3], src);
        e4[q] = __shfl(enq[j & 3], src);
        const u16* nb = h + (long)cc4[q] * 128 + seg * 32;
        nv[q * 4 + 0] = *(const uint4*)(nb);
        nv[q * 4 + 1] = *(const uint4*)(nb + 8);
        nv[q * 4 + 2] = *(const uint4*)(nb + 16);
        nv[q * 4 + 3] = *(const uint4*)(nb + 24);
      }
#pragma unroll
      for (int q = 0; q < 4; q++) {
        float e = e4[q];
#pragma unroll
        for (int v = 0; v < 4; v++) {
          const u16* pv = (const u16*)&nv[q * 4 + v];
#pragma unroll
          for (int i = 0; i < 8; i++) acc[v * 8 + i] += e * b2f(pv[i]);
        }
      }
    }
    u16 ob[32];
#pragma unroll
    for (int i = 0; i < 32; i++) ob[i] = f2b(acc[i]);
    uint4* o4 = (uint4*)(sA + row * 132 + seg * 32);
    uint4* s4 = (uint4*)ob;
#pragma unroll
    for (int i = 0; i < 4; i++) o4[i] = s4[i];
  }
  __syncthreads();
  int wave = t >> 6, m = lane & 15, g = lane >> 4;
  const u16* aB = sA + (wave * 16 + m) * 132 + g * 8;
  short8 a[4];
#pragma unroll
  for (int s = 0; s < 4; s++) a[s] = *(const short8*)(aB + s * 32);
  f32x4 acc[8];
#pragma unroll
  for (int c = 0; c < 8; c++) {
    float bc = gb[c * 16 + m];
    acc[c] = (f32x4){bc, bc, bc, bc};
  }
#pragma unroll
  for (int s = 0; s < 4; s++) {
#pragma unroll
    for (int c = 0; c < 8; c++) {
      short8 bb = *(const short8*)(sW + (c * 16 + m) * 132 + g * 8 + s * 32);
      acc[c] = __builtin_amdgcn_mfma_f32_16x16x32_bf16(a[s], bb, acc[c], 0, 0, 0);
    }
  }
#pragma unroll
  for (int c = 0; c < 8; c++) {
    int col = c * 16 + m;
#pragma unroll
    for (int r = 0; r < 4; r++) {
      float y = acc[c][r];
      if (relu) y = fmaxf(y, 0.f);
      out[(n0 + wave * 16 + g * 4 + r) * 128 + col] = f2b(y);
    }
  }
}

// ---------------------------------------------------------------- Gram: 2 slices/block, Gpart[128], + zsum
__global__ __launch_bounds__(256) void k_gram(const u16* __restrict__ z0T,
                                              float* __restrict__ Gpart, float* __restrict__ zsum) {
  __shared__ u16 sZT[128 * 264];
  int t = threadIdx.x;
  int wave = t >> 6, lane = t & 63, m = lane & 15, g = lane >> 4;
  f32x4 acc[2][8];
#pragma unroll
  for (int i = 0; i < 2; i++)
#pragma unroll
    for (int c = 0; c < 8; c++) acc[i][c] = (f32x4){0.f, 0.f, 0.f, 0.f};
  float zs = 0.f;
  for (int sl = 0; sl < 2; sl++) {
    long k0 = (long)(blockIdx.x * 2 + sl) * 256;
    __syncthreads();
#pragma unroll
    for (int i = 0; i < 16; i++) {
      int idx = t + i * 256; int mm = idx >> 5, ch = idx & 31;
      *(float4*)(sZT + mm * 264 + ch * 8) = *(const float4*)(z0T + (long)mm * BNn + k0 + ch * 8);
    }
    __syncthreads();
#pragma unroll
    for (int kk = 0; kk < 8; kk++) {
      short8 a0 = *(const short8*)(sZT + (wave * 32 + m) * 264 + kk * 32 + g * 8);
      short8 a1 = *(const short8*)(sZT + (wave * 32 + 16 + m) * 264 + kk * 32 + g * 8);
#pragma unroll
      for (int c = 0; c < 8; c++) {
        short8 bb = *(const short8*)(sZT + (c * 16 + m) * 264 + kk * 32 + g * 8);
        acc[0][c] = __builtin_amdgcn_mfma_f32_16x16x32_bf16(a0, bb, acc[0][c], 0, 0, 0);
        acc[1][c] = __builtin_amdgcn_mfma_f32_16x16x32_bf16(a1, bb, acc[1][c], 0, 0, 0);
      }
    }
    if (t < 128) {
      float s = 0.f;
      for (int j = 0; j < 256; j++) s += b2f(sZT[t * 264 + j]);
      zs += s;
    }
  }
  if (t < 128) atomicAdd(&zsum[t], zs);
  float* P = Gpart + (long)blockIdx.x * 16384 + wave * 4096;
#pragma unroll
  for (int i = 0; i < 2; i++)
#pragma unroll
    for (int c = 0; c < 8; c++)
      *(f32x4*)(P + (i * 8 + c) * 256 + lane * 4) = acc[i][c];
}

// ---------------------------------------------------------------- reduce Gram partials -> G fp32 [128][128]
__global__ void k_gram_red(const float* __restrict__ Gpart, float* __restrict__ G) {
  int o = blockIdx.x * 256 + threadIdx.x;   // 0..16383
  float s = 0.f;
  for (int b = 0; b < 128; b++) s += Gpart[(long)b * 16384 + o];
  int wave = o >> 12, rem = o & 4095;
  int ic = rem >> 8, i = ic >> 3, c = ic & 7;
  int rem2 = rem & 255, lane = rem2 >> 2, q = rem2 & 3;
  int m = lane & 15, g = lane >> 4;
  int mi = wave * 32 + i * 16 + g * 4 + q;
  int mj = c * 16 + m;
  G[mi * 128 + mj] = s;
}

// ---------------------------------------------------------------- merged stats + kvsT
__global__ __launch_bounds__(256) void k_statskvs(const float* __restrict__ Wq, const float* __restrict__ bq,
                                                  const float* __restrict__ Wk, const float* __restrict__ bk,
                                                  const float* __restrict__ Wv, const float* __restrict__ bv,
                                                  const float* __restrict__ G, const float* __restrict__ zsum,
                                                  float* __restrict__ ksum,
                                                  float* __restrict__ Sq, float* __restrict__ Sk,
                                                  u16* __restrict__ kvsT) {
  int t = threadIdx.x;
  int blk = blockIdx.x;
  if (blk < 2) {
    int c = blk * 256 + t;
    float s = 0.f;
    for (int i = 0; i < 128; i++) s += Wk[i * 512 + c] * zsum[i];
    ksum[c] = s + 65536.0f * bk[c];
    return;
  }
  if (blk < 130) {
    __shared__ float wcol[128];
    __shared__ float red[256];
    int bi = blk - 2;
    int isK = bi >> 6;
    const float* W = isK ? Wk : Wq;
    const float* bb = isK ? bk : bq;
    float* S = isK ? Sk : Sq;
    int c0 = (bi & 63) * 8;
    float tot = 0.f;
    for (int cc = 0; cc < 8; cc++) {
      int c = c0 + cc;
      __syncthreads();
      if (t < 128) wcol[t] = W[t * 512 + c];
      __syncthreads();
      float v = 0.f;
      if (t < 128) {
        float uu = 0.f;
        for (int j = 0; j < 128; j++) uu += G[t * 128 + j] * wcol[j];
        v = uu * wcol[t] + 2.0f * bb[c] * wcol[t] * zsum[t];
      }
      red[t] = v;
      __syncthreads();
      for (int o = 128; o > 0; o >>= 1) { if (t < o) red[t] += red[t + o]; __syncthreads(); }
      if (t == 0) tot += red[0] + 65536.0f * bb[c] * bb[c];
    }
    if (t == 0) atomicAdd(S, tot);
    return;
  }
  {
    __shared__ float wv8[128][8];
    __shared__ float U[128][8];
    __shared__ float zv[8];
    int bi = blk - 130;
    int h = bi >> 4, dg = bi & 15;
    if (t < 128) {
#pragma unroll
      for (int dd = 0; dd < 8; dd++) wv8[t][dd] = Wv[t * 512 + h * 128 + dg * 8 + dd];
    }
    __syncthreads();
    {
      int i = t & 127, du = t >> 7;
      float a0 = 0.f, a1 = 0.f, a2 = 0.f, a3 = 0.f;
      for (int j = 0; j < 128; j++) {
        float gg = G[i * 128 + j];
        a0 += gg * wv8[j][du * 4 + 0]; a1 += gg * wv8[j][du * 4 + 1];
        a2 += gg * wv8[j][du * 4 + 2]; a3 += gg * wv8[j][du * 4 + 3];
      }
      U[i][du * 4 + 0] = a0; U[i][du * 4 + 1] = a1; U[i][du * 4 + 2] = a2; U[i][du * 4 + 3] = a3;
    }
    if (t < 8) {
      float s = 0.f;
      for (int i = 0; i < 128; i++) s += zsum[i] * wv8[i][t];
      zv[t] = s;
    }
    __syncthreads();
    {
      int m = t & 127, du = t >> 7;
      int colk = h * 128 + m;
      float bkm = bk[colk];
      float a[4] = {0.f, 0.f, 0.f, 0.f};
      float wkzs = 0.f;
      for (int i = 0; i < 128; i++) {
        float wk = Wk[i * 512 + colk];
        wkzs += wk * zsum[i];
#pragma unroll
        for (int q = 0; q < 4; q++) a[q] += wk * U[i][du * 4 + q];
      }
#pragma unroll
      for (int q = 0; q < 4; q++) {
        int dd = du * 4 + q;
        int cold = h * 128 + dg * 8 + dd;
        float val = a[q] + wkzs * bv[cold] + bkm * zv[dd] + 65536.0f * bkm * bv[cold];
        kvsT[h * 16384 + (dg * 8 + dd) * 128 + m] = f2b(val);
      }
    }
  }
}

// ---------------------------------------------------------------- prepB: M_h = inv*(Wq_h@kvs_h) + 65536*Wv_h
__global__ __launch_bounds__(256) void k_prepB(const float* __restrict__ Wq, const float* __restrict__ bq,
                                               const float* __restrict__ Wv, const float* __restrict__ bv,
                                               const u16* __restrict__ kvsT, const float* __restrict__ ksum,
                                               const float* __restrict__ SqSk,
                                               u16* __restrict__ Bmat, float* __restrict__ cAv,
                                               u16* __restrict__ U16, float* __restrict__ consts) {
  __shared__ float kvr[8][128];
  int t = threadIdx.x;
  int h = blockIdx.x >> 4, dg = blockIdx.x & 15;
  float inv = rsqrtf(SqSk[0] * SqSk[1]);
  for (int i = t; i < 1024; i += 256) {
    int dl = i >> 7, m = i & 127;
    kvr[dl][m] = b2f(kvsT[h * 16384 + (dg * 8 + dl) * 128 + m]);
  }
  __syncthreads();
  {
    int k = t & 127, du = t >> 7;
    const float* wqr = Wq + k * 512 + h * 128;
    float acc[4] = {0.f, 0.f, 0.f, 0.f};
    for (int m = 0; m < 128; m++) {
      float w = wqr[m];
#pragma unroll
      for (int q = 0; q < 4; q++) acc[q] += w * kvr[du * 4 + q][m];
    }
#pragma unroll
    for (int q = 0; q < 4; q++) {
      int dd = dg * 8 + du * 4 + q;
      float mv = acc[q] * inv + 65536.0f * Wv[k * 512 + h * 128 + dd];
      Bmat[((long)h * 128 + dd) * 128 + k] = f2b(mv);
    }
  }
  if (t < 8) {
    float s = 0.f;
    for (int m = 0; m < 128; m++) s += bq[h * 128 + m] * kvr[t][m];
    cAv[h * 128 + dg * 8 + t] = s * inv + 65536.0f * bv[h * 128 + dg * 8 + t];
  }
  if (dg == 0) {
    if (t < 128) {
      float s = 0.f;
      for (int m = 0; m < 128; m++) s += Wq[t * 512 + h * 128 + m] * ksum[h * 128 + m];
      U16[h * 128 + t] = f2b(s * inv);
    } else if (t == 128) {
      float s = 0.f;
      for (int m = 0; m < 128; m++) s += bq[h * 128 + m] * ksum[h * 128 + m];
      consts[h] = s * inv + 65536.0f;
    }
    if (h == 0) {
      for (int i = t; i < 1536; i += 256) U16[512 + i] = 0;
    }
  }
}

// ---------------------------------------------------------------- mega-fused: attn+LN2+blend -> sg -> enh
// v5 (r8-verified): 256 threads / 4 waves, 32 rows/wave, plain LDS staging.
__global__ __launch_bounds__(256, 2) void k_numfuse(const u16* __restrict__ z0, const u16* __restrict__ gnn,
                                                 const u16* __restrict__ Bmat,
                                                 const float* __restrict__ cAv, const u16* __restrict__ U16,
                                                 const float* __restrict__ consts,
                                                 const float* __restrict__ g2, const float* __restrict__ b2,
                                                 const u16* __restrict__ wsg, const float* __restrict__ sgb,
                                                 u16* __restrict__ enh) {
  __shared__ u16 sA[128 * 132];
  __shared__ u16 sB[128 * 132];
  __shared__ float rden[512];
  __shared__ float caL[512];
  int t = threadIdx.x;
  long n0 = (long)blockIdx.x * 128;
  int wave = t >> 6, lane = t & 63, m = lane & 15, g = lane >> 4;
  u16* myA = sA + wave * 32 * 132;
  {
    const u16* zg = z0 + (n0 + wave * 32) * 128;
#pragma unroll
    for (int i = 0; i < 8; i++) {
      int idx = lane + i * 64;
      *(float4*)(myA + idx * 8 + (idx >> 4) * 4) = *(const float4*)(zg + idx * 8);
    }
  }
  caL[t] = cAv[t]; caL[t + 256] = cAv[t + 256];
  const u16* aB = sA + (wave * 32 + m) * 132 + g * 8;
  short8 a[2][4];
#pragma unroll
  for (int i = 0; i < 2; i++)
#pragma unroll
    for (int s = 0; s < 4; s++) a[i][s] = *(const short8*)(aB + i * 16 * 132 + s * 32);
  {
    f32x4 accd0 = (f32x4){0.f, 0.f, 0.f, 0.f}, accd1 = (f32x4){0.f, 0.f, 0.f, 0.f};
#pragma unroll
    for (int s = 0; s < 4; s++) {
      short8 ub = *(const short8*)(U16 + m * 128 + g * 8 + s * 32);
      accd0 = __builtin_amdgcn_mfma_f32_16x16x32_bf16(a[0][s], ub, accd0, 0, 0, 0);
      accd1 = __builtin_amdgcn_mfma_f32_16x16x32_bf16(a[1][s], ub, accd1, 0, 0, 0);
    }
    if (m < 4) {
      float ch = consts[m];
#pragma unroll
      for (int r = 0; r < 4; r++) {
        rden[(wave * 32 + g * 4 + r) * 4 + m] = 1.0f / (accd0[r] + ch);
        rden[(wave * 32 + 16 + g * 4 + r) * 4 + m] = 1.0f / (accd1[r] + ch);
      }
    }
  }
  f32x4 attn[2][8];
#pragma unroll
  for (int i = 0; i < 2; i++)
#pragma unroll
    for (int c = 0; c < 8; c++) attn[i][c] = (f32x4){0.f, 0.f, 0.f, 0.f};
  for (int h = 0; h < 4; h++) {
    __syncthreads();
    {
      const u16* src = Bmat + (long)h * 16384;
#pragma unroll
      for (int i = 0; i < 8; i++) {
        int idx = t + i * 256;
        *(float4*)(sB + idx * 8 + (idx >> 4) * 4) = *(const float4*)(src + idx * 8);
      }
    }
    __syncthreads();
    f32x4 acc[2][8];
#pragma unroll
    for (int c = 0; c < 8; c++) {
      float ca = caL[h * 128 + c * 16 + m];
      acc[0][c] = (f32x4){ca, ca, ca, ca};
      acc[1][c] = (f32x4){ca, ca, ca, ca};
    }
#pragma unroll
    for (int s = 0; s < 4; s++) {
#pragma unroll
      for (int c = 0; c < 8; c++) {
        short8 bb = *(const short8*)(sB + (c * 16 + m) * 132 + g * 8 + s * 32);
        acc[0][c] = __builtin_amdgcn_mfma_f32_16x16x32_bf16(a[0][s], bb, acc[0][c], 0, 0, 0);
        acc[1][c] = __builtin_amdgcn_mfma_f32_16x16x32_bf16(a[1][s], bb, acc[1][c], 0, 0, 0);
      }
    }
    float rd0[4], rd1[4];
#pragma unroll
    for (int r = 0; r < 4; r++) {
      rd0[r] = rden[(wave * 32 + g * 4 + r) * 4 + h];
      rd1[r] = rden[(wave * 32 + 16 + g * 4 + r) * 4 + h];
    }
#pragma unroll
    for (int c = 0; c < 8; c++)
#pragma unroll
      for (int r = 0; r < 4; r++) {
        attn[0][c][r] += acc[0][c][r] * rd0[r];
        attn[1][c][r] += acc[1][c][r] * rd1[r];
      }
  }
  float4 gv[8];
  {
    const u16* gg = gnn + (n0 + wave * 32) * 128;
#pragma unroll
    for (int i = 0; i < 8; i++) {
      int idx = lane + i * 64;
      gv[i] = *(const float4*)(gg + idx * 8);
    }
  }
  float y[2][8][4];
#pragma unroll
  for (int i = 0; i < 2; i++)
#pragma unroll
    for (int c = 0; c < 8; c++)
#pragma unroll
      for (int r = 0; r < 4; r++)
        y[i][c][r] = 0.125f * attn[i][c][r] + 0.5f * b2f(sA[(wave * 32 + i * 16 + g * 4 + r) * 132 + c * 16 + m]);
  float mu[2][4], rstd[2][4];
#pragma unroll
  for (int i = 0; i < 2; i++)
#pragma unroll
    for (int r = 0; r < 4; r++) {
      float s1 = 0.f, s2 = 0.f;
#pragma unroll
      for (int c = 0; c < 8; c++) { float v = y[i][c][r]; s1 += v; s2 += v * v; }
#pragma unroll
      for (int mask = 1; mask < 16; mask <<= 1) { s1 += __shfl_xor(s1, mask); s2 += __shfl_xor(s2, mask); }
      float mm2 = s1 * (1.f / 128.f);
      mu[i][r] = mm2; rstd[i][r] = rsqrtf(s2 * (1.f / 128.f) - mm2 * mm2 + 1e-5f);
    }
#pragma unroll
  for (int i = 0; i < 8; i++) {
    int idx = lane + i * 64;
    *(float4*)(myA + idx * 8 + (idx >> 4) * 4) = gv[i];
  }
#pragma unroll
  for (int c = 0; c < 8; c++) {
    int d = c * 16 + m;
    float ggc = g2[d], bbc = b2[d];
#pragma unroll
    for (int i = 0; i < 2; i++)
#pragma unroll
      for (int r = 0; r < 4; r++) {
        int loc = (wave * 32 + i * 16 + g * 4 + r) * 132 + d;
        float zr = fmaxf((y[i][c][r] - mu[i][r]) * rstd[i][r] * ggc + bbc, 0.f);
        sA[loc] = f2b(0.8f * b2f(sA[loc]) + 0.2f * zr);
      }
  }
  __syncthreads();
  {
#pragma unroll
    for (int i = 0; i < 8; i++) {
      int idx = t + i * 256;
      *(float4*)(sB + idx * 8 + (idx >> 4) * 4) = *(const float4*)(wsg + idx * 8);
    }
  }
  __syncthreads();
  short8 ap[2][4];
#pragma unroll
  for (int i = 0; i < 2; i++)
#pragma unroll
    for (int s = 0; s < 4; s++) ap[i][s] = *(const short8*)(aB + i * 16 * 132 + s * 32);
  f32x4 acc2[2][8];
#pragma unroll
  for (int c = 0; c < 8; c++) {
    float bc = sgb[c * 16 + m];
    acc2[0][c] = (f32x4){bc, bc, bc, bc};
    acc2[1][c] = (f32x4){bc, bc, bc, bc};
  }
#pragma unroll
  for (int s = 0; s < 4; s++) {
#pragma unroll
    for (int c = 0; c < 8; c++) {
      short8 bb = *(const short8*)(sB + (c * 16 + m) * 132 + g * 8 + s * 32);
      acc2[0][c] = __builtin_amdgcn_mfma_f32_16x16x32_bf16(ap[0][s], bb, acc2[0][c], 0, 0, 0);
      acc2[1][c] = __builtin_amdgcn_mfma_f32_16x16x32_bf16(ap[1][s], bb, acc2[1][c], 0, 0, 0);
    }
  }
#pragma unroll
  for (int i = 0; i < 2; i++)
#pragma unroll
    for (int c = 0; c < 8; c++) {
      int d = c * 16 + m;
#pragma unroll
      for (int r = 0; r < 4; r++)
        enh[(n0 + wave * 32 + i * 16 + g * 4 + r) * 128 + d] = f2b(acc2[i][c][r]);
    }
}

// ---------------------------------------------------------------- k_dec v5: v2 body (measured best) + fused single-pass
// softmax (waves 0-3 do max+exp+sum in regs; saves 2 full-block barriers).
// Verified r10: 56.8-58.1us, passed.
__global__ __launch_bounds__(1024) void k_dec(const u16* __restrict__ enh, const int* __restrict__ cidx,
                                             const int* __restrict__ vps,
                                             const float* __restrict__ dWq, const float* __restrict__ dWk,
                                             const float* __restrict__ dWv, const float* __restrict__ dWo,
                                             const float* __restrict__ ln1g, const float* __restrict__ ln1b,
                                             const float* __restrict__ fW1, const float* __restrict__ fb1,
                                             const float* __restrict__ fW2, const float* __restrict__ fb2,
                                             const float* __restrict__ ln2g, const float* __restrict__ ln2b,
                                             const float* __restrict__ qW, const float* __restrict__ qb,
                                             float* __restrict__ out) {
  __shared__ float cur[128], qd[128], qtL[4][128];
  __shared__ float scL[4][1024];
  __shared__ float dinvs[4];
  __shared__ float pvL[16][4][128];
  __shared__ float sH[4][128];
  __shared__ float att[128], tn[128], tv[128], f1[512], glob[128];
  __shared__ float red[16], red2[16];
  __shared__ float mu_s, rs_s, base_s;
  int b = blockIdx.x, t = threadIdx.x;
  int wave = t >> 6, lane = t & 63;
  const u16* eb = enh + (long)b * 1024 * 128;
  if (t < 128) cur[t] = b2f(eb[(long)cidx[b] * 128 + t]);
  __syncthreads();
  {
    int o = t >> 3, p = t & 7;
    float s = 0.f;
    int k0 = p * 16;
#pragma unroll
    for (int k = 0; k < 16; k++) s += cur[k0 + k] * dWq[(k0 + k) * 128 + o];
    s += __shfl_xor(s, 1); s += __shfl_xor(s, 2); s += __shfl_xor(s, 4);
    if (p == 0) qd[o] = s;
  }
  __syncthreads();
  if (t < 512) {
    int h = t >> 7, col = t & 127;
    float s = 0.f;
#pragma unroll
    for (int c = 0; c < 32; c++) s += dWk[col * 128 + h * 32 + c] * qd[h * 32 + c];
    qtL[h][col] = s;
  }
  __syncthreads();
  const float scale = 0.17677669529663687f;
  {
    const u16* er = eb + (long)t * 128;
    float s0 = 0.f, s1 = 0.f, s2 = 0.f, s3 = 0.f;
#pragma unroll
    for (int i8 = 0; i8 < 16; i8++) {
      short8 ev = *(const short8*)(er + i8 * 8);
#pragma unroll
      for (int j = 0; j < 8; j++) {
        float e = b2f((u16)ev[j]);
        int k = i8 * 8 + j;
        s0 += e * qtL[0][k]; s1 += e * qtL[1][k]; s2 += e * qtL[2][k]; s3 += e * qtL[3][k];
      }
    }
    scL[0][t] = s0 * scale; scL[1][t] = s1 * scale; scL[2][t] = s2 * scale; scL[3][t] = s3 * scale;
  }
  __syncthreads();
  // fused softmax: waves 0-3, one head each, single pass
  if (wave < 4) {
    float v[16];
    float mx = -3.0e38f;
#pragma unroll
    for (int i = 0; i < 16; i++) { v[i] = scL[wave][lane + i * 64]; mx = fmaxf(mx, v[i]); }
#pragma unroll
    for (int msk = 1; msk < 64; msk <<= 1) mx = fmaxf(mx, __shfl_xor(mx, msk));
    float sm = 0.f;
#pragma unroll
    for (int i = 0; i < 16; i++) { float e = __expf(v[i] - mx); scL[wave][lane + i * 64] = e; sm += e; }
#pragma unroll
    for (int msk = 1; msk < 64; msk <<= 1) sm += __shfl_xor(sm, msk);
    if (lane == 0) dinvs[wave] = 1.0f / sm;
  }
  __syncthreads();
  {
    int seg = t & 15, part = t >> 4;
    float acc[4][8];
#pragma unroll
    for (int h = 0; h < 4; h++)
#pragma unroll
      for (int j = 0; j < 8; j++) acc[h][j] = 0.f;
    for (int i = 0; i < 16; i++) {
      int n = part * 16 + i;
      short8 e8 = *(const short8*)(eb + (long)n * 128 + seg * 8);
      float p0 = scL[0][n], p1 = scL[1][n], p2 = scL[2][n], p3 = scL[3][n];
#pragma unroll
      for (int j = 0; j < 8; j++) {
        float e = b2f((u16)e8[j]);
        acc[0][j] += p0 * e; acc[1][j] += p1 * e; acc[2][j] += p2 * e; acc[3][j] += p3 * e;
      }
    }
#pragma unroll
    for (int h = 0; h < 4; h++)
#pragma unroll
      for (int j = 0; j < 8; j++) {
        acc[h][j] += __shfl_xor(acc[h][j], 16);
        acc[h][j] += __shfl_xor(acc[h][j], 32);
      }
    if (lane < 16) {
#pragma unroll
      for (int h = 0; h < 4; h++)
#pragma unroll
        for (int j = 0; j < 8; j++) pvL[wave][h][seg * 8 + j] = acc[h][j];
    }
  }
  __syncthreads();
  if (t < 512) {
    int h = t >> 7, d = t & 127;
    float s = 0.f;
#pragma unroll
    for (int w = 0; w < 16; w++) s += pvL[w][h][d];
    sH[h][d] = s;
  }
  __syncthreads();
  {
    int o = t >> 3, p = t & 7;
    int h = o >> 5, e = o & 31;
    float s = 0.f;
    int k0 = p * 16;
#pragma unroll
    for (int k = 0; k < 16; k++) s += sH[h][k0 + k] * dWv[(k0 + k) * 128 + h * 32 + e];
    s += __shfl_xor(s, 1); s += __shfl_xor(s, 2); s += __shfl_xor(s, 4);
    if (p == 0) att[o] = s * dinvs[h];
  }
  __syncthreads();
  {
    int o = t >> 3, p = t & 7;
    float s = 0.f;
    int k0 = p * 16;
#pragma unroll
    for (int k = 0; k < 16; k++) s += att[k0 + k] * dWo[(k0 + k) * 128 + o];
    s += __shfl_xor(s, 1); s += __shfl_xor(s, 2); s += __shfl_xor(s, 4);
    if (p == 0) tv[o] = cur[o] + s;
  }
  __syncthreads();
  {
    float v = (t < 128) ? tv[t] : 0.f;
    float s1 = v, s2 = v * v;
#pragma unroll
    for (int msk = 1; msk < 64; msk <<= 1) { s1 += __shfl_xor(s1, msk); s2 += __shfl_xor(s2, msk); }
    if (lane == 0) { red[wave] = s1; red2[wave] = s2; }
  }
  __syncthreads();
  if (t == 0) {
    float s1 = 0.f, s2 = 0.f;
#pragma unroll
    for (int w = 0; w < 16; w++) { s1 += red[w]; s2 += red2[w]; }
    float mm = s1 / 128.0f;
    mu_s = mm; rs_s = rsqrtf(s2 / 128.0f - mm * mm + 1e-5f);
  }
  __syncthreads();
  if (t < 128) tn[t] = (tv[t] - mu_s) * rs_s * ln1g[t] + ln1b[t];
  __syncthreads();
  if (t < 512) {
    float s = fb1[t];
    for (int k = 0; k < 128; k++) s += tn[k] * fW1[k * 512 + t];
    f1[t] = fmaxf(s, 0.0f);
  }
  __syncthreads();
  {
    int o = t >> 3, p = t & 7;
    float s = 0.f;
    int k0 = p * 64;
#pragma unroll
    for (int k = 0; k < 64; k++) s += f1[k0 + k] * fW2[(k0 + k) * 128 + o];
    s += __shfl_xor(s, 1); s += __shfl_xor(s, 2); s += __shfl_xor(s, 4);
    if (p == 0) tv[o] = tn[o] + s + fb2[o];
  }
  __syncthreads();
  {
    float v = (t < 128) ? tv[t] : 0.f;
    float s1 = v, s2 = v * v;
#pragma unroll
    for (int msk = 1; msk < 64; msk <<= 1) { s1 += __shfl_xor(s1, msk); s2 += __shfl_xor(s2, msk); }
    if (lane == 0) { red[wave] = s1; red2[wave] = s2; }
  }
  __syncthreads();
  if (t == 0) {
    float s1 = 0.f, s2 = 0.f;
#pragma unroll
    for (int w = 0; w < 16; w++) { s1 += red[w]; s2 += red2[w]; }
    float mm = s1 / 128.0f;
    mu_s = mm; rs_s = rsqrtf(s2 / 128.0f - mm * mm + 1e-5f);
  }
  __syncthreads();
  if (t < 128) glob[t] = (tv[t] - mu_s) * rs_s * ln2g[t] + ln2b[t];
  __syncthreads();
  {
    float v = 0.f;
    if (t < 256) v = (t < 128 ? glob[t] : cur[t - 128]) * qW[t];
    float s = v;
#pragma unroll
    for (int msk = 1; msk < 64; msk <<= 1) s += __shfl_xor(s, msk);
    if (lane == 0) red[wave] = s;
  }
  __syncthreads();
  if (t == 0) {
    float s = 0.f;
#pragma unroll
    for (int w = 0; w < 16; w++) s += red[w];
    base_s = s + qb[0];
  }
  __syncthreads();
  {
    int o = t >> 3, p = t & 7;
    int vi = vps[b * 128 + o];
    const u16* er = eb + (long)vi * 128 + p * 16;
    short8 e0 = *(const short8*)(er);
    short8 e1 = *(const short8*)(er + 8);
    float s = 0.f;
#pragma unroll
    for (int j = 0; j < 8; j++) {
      s += b2f((u16)e0[j]) * qW[256 + p * 16 + j];
      s += b2f((u16)e1[j]) * qW[256 + p * 16 + 8 + j];
    }
    s += __shfl_xor(s, 1); s += __shfl_xor(s, 2); s += __shfl_xor(s, 4);
    if (p == 0) out[b * 128 + o] = base_s + s;
  }
}

// ================================================================ launch
extern "C" void kernel_launch(void* const* d_in, const int* in_sizes, int n_in,
                              void* d_out, int out_size, void* d_ws, size_t ws_size,
                              hipStream_t stream) {
  const float* node_in = (const float*)d_in[0];
  const int* cur_idx   = (const int*)d_in[2];
  const int* vps       = (const int*)d_in[3];
  const int* adj       = (const int*)d_in[5];
  const float* W_init  = (const float*)d_in[6];
  const float* b_init  = (const float*)d_in[7];
  const float* gcn_W   = (const float*)d_in[8];
  const float* gcn_b   = (const float*)d_in[9];
  const float* tc_fc_W = (const float*)d_in[10];
  const float* tc_fc_b = (const float*)d_in[11];
  const float* ln1g    = (const float*)d_in[12];
  const float* ln1b    = (const float*)d_in[13];
  const float* Wq      = (const float*)d_in[14];
  const float* bq      = (const float*)d_in[15];
  const float* Wk      = (const float*)d_in[16];
  const float* bk      = (const float*)d_in[17];
  const float* Wv      = (const float*)d_in[18];
  const float* bv      = (const float*)d_in[19];
  const float* ln2g    = (const float*)d_in[20];
  const float* ln2b    = (const float*)d_in[21];
  const float* sg_W    = (const float*)d_in[22];
  const float* sg_b    = (const float*)d_in[23];
  const float* dWq     = (const float*)d_in[24];
  const float* dWk     = (const float*)d_in[25];
  const float* dWv     = (const float*)d_in[26];
  const float* dWo     = (const float*)d_in[27];
  const float* dln1g   = (const float*)d_in[28];
  const float* dln1b   = (const float*)d_in[29];
  const float* fW1     = (const float*)d_in[30];
  const float* fb1     = (const float*)d_in[31];
  const float* fW2     = (const float*)d_in[32];
  const float* fb2     = (const float*)d_in[33];
  const float* dln2g   = (const float*)d_in[34];
  const float* dln2b   = (const float*)d_in[35];
  const float* qW      = (const float*)d_in[36];
  const float* qb      = (const float*)d_in[37];

  char* base = (char*)d_ws;
  u16* bufA = (u16*)base;                           // x0 -> gcn ping -> gnn
  u16* bufB = (u16*)(base + 16777216);              // z0 -> enh
  u16* bufC = (u16*)(base + 33554432);              // gcn temp
  u16* z0T  = (u16*)(base + 50331648);              // [128][BN]
  float* Gpart = (float*)(base + 67108864);         // [128][16384]
  char* sm = base + 83886080;
  u16* kvsT   = (u16*)sm;                           // 65536 u16
  u16* wts    = (u16*)(sm + 131072);                // 327680 u16
  float* bqkv = (float*)(sm + 131072 + 655360);     // 1536 (unused slot)
  float* ksum = bqkv + 1536;                        // 512
  float* SqSk = ksum + 512;                         // 2
  float* zsum = SqSk + 2;                           // 128
  float* Gm   = zsum + 128;                         // 16384
  float* dinv = Gm + 16384;                         // 65536
  float* cAv  = dinv + BNn;                         // 512
  float* consts = cAv + 512;                        // 4
  u16* Bmat = (u16*)(consts + 4);                   // 65536 u16
  u16* U16m = Bmat + 65536;                         // 2048 u16

  // prep + embed + deg + zero (merged)
  k_init<<<2089, 256, 0, stream>>>(gcn_W, tc_fc_W, sg_W, dWk, dWv, Wq, Wk, Wv,
                                   node_in, W_init, b_init, adj, dinv, wts, SqSk, bufA);

  // z0 = relu(LN(x0 @ tc_fc + b)) -> bufB (+ z0T)
  k_gemm<2><<<512, 256, 0, stream>>>(bufA, wts + 4 * 16384, tc_fc_b, ln1g, ln1b, bufB, z0T);

  // Gram chain -> analytic stats/kvs -> merged M matrices
  k_gram<<<128, 256, 0, stream>>>(z0T, Gpart, zsum);
  k_gram_red<<<64, 256, 0, stream>>>(Gpart, Gm);
  k_statskvs<<<194, 256, 0, stream>>>(Wq, bq, Wk, bk, Wv, bv, Gm, zsum, ksum, SqSk, SqSk + 1, kvsT);
  k_prepB<<<64, 256, 0, stream>>>(Wq, bq, Wv, bv, kvsT, ksum, SqSk, Bmat, cAv, U16m, consts);

  // fused GCN x4 (XCD-locality swizzle; v2 batched gather)
  k_gcn<<<1024, 256, 0, stream>>>(bufA, wts + 0 * 16384, adj, dinv, gcn_b + 0, bufC, 1);
  k_gcn<<<1024, 256, 0, stream>>>(bufC, wts + 1 * 16384, adj, dinv, gcn_b + 128, bufA, 1);
  k_gcn<<<1024, 256, 0, stream>>>(bufA, wts + 2 * 16384, adj, dinv, gcn_b + 256, bufC, 1);
  k_gcn<<<1024, 256, 0, stream>>>(bufC, wts + 3 * 16384, adj, dinv, gcn_b + 384, bufA, 0);  // gnn -> bufA

  // mega-fused attention combine + sg -> enh (v5)
  k_numfuse<<<512, 256, 0, stream>>>(bufB, bufA, Bmat, cAv, U16m, consts, ln2g, ln2b,
                                     wts + 5 * 16384, sg_b, bufB);

  // fused decoder v5 (v2 + fused softmax)
  k_dec<<<64, 1024, 0, stream>>>(bufB, cur_idx, vps, dWq, dWk, dWv, dWo, dln1g, dln1b,
                                 fW1, fb1, fW2, fb2, dln2g, dln2b, qW, qb, (float*)d_out);
}